// Round 1
// baseline (704.386 us; speedup 1.0000x reference)
//
#include <hip/hip_runtime.h>
#include <hip/hip_cooperative_groups.h>
#include <cmath>

namespace cg = cooperative_groups;

// Tree constants (complete 4-ary tree, depth 7)
constexpr int N_NODES = 21845;
constexpr int N_INT   = 5461;   // internal nodes (levels 0..6)
constexpr int HID     = 512;

typedef short  short8  __attribute__((ext_vector_type(8)));
typedef float  floatx4 __attribute__((ext_vector_type(4)));

// fp32 -> bf16 bit pattern, round-to-nearest-even
__device__ __forceinline__ unsigned short f2bf(float f) {
    unsigned int u = __float_as_uint(f);
    u += 0x7fffu + ((u >> 16) & 1u);
    return (unsigned short)(u >> 16);
}

#define GLD_LDS(g, l) __builtin_amdgcn_global_load_lds( \
    (const __attribute__((address_space(1))) void*)(g), \
    (__attribute__((address_space(3))) void*)(l), 16, 0, 0)

// ================= prep body: zero leaf h/c rows + cast all GEMM operands to bf16 ============
__device__ __forceinline__ void prep_body(const float* __restrict__ x,
                                          const float* __restrict__ W_iou,
                                          const float* __restrict__ W_f,
                                          const float* __restrict__ U_iou,
                                          const float* __restrict__ U_f,
                                          float* __restrict__ h_leaf,
                                          float* __restrict__ c_leaf,
                                          unsigned short* __restrict__ dstb)
{
    const size_t Z  = (size_t)(N_NODES - N_INT) * HID / 4;   // float4 per leaf region
    const size_t C0 = (size_t)N_INT * 512 / 4;               // xb
    const size_t C1 = C0 + 1536 * 512 / 4;                   // + W_iou
    const size_t C2 = C1 + 512 * 512 / 4;                    // + W_f
    const size_t C3 = C2 + 1536 * 512 / 4;                   // + U_iou
    const size_t C4 = C3 + 512 * 512 / 4;                    // + U_f
    const size_t total = 2 * Z + C4;
    size_t i = (size_t)blockIdx.x * blockDim.x + threadIdx.x;
    const size_t stride = (size_t)gridDim.x * blockDim.x;
    const float4 zz = {0.f, 0.f, 0.f, 0.f};
    for (; i < total; i += stride) {
        if (i < 2 * Z) {
            if (i < Z) ((float4*)h_leaf)[i] = zz;
            else       ((float4*)c_leaf)[i - Z] = zz;
        } else {
            size_t k = i - 2 * Z;
            const float* src; size_t off;
            if (k < C0)      { src = x;     off = k; }
            else if (k < C1) { src = W_iou; off = k - C0; }
            else if (k < C2) { src = W_f;   off = k - C1; }
            else if (k < C3) { src = U_iou; off = k - C2; }
            else             { src = U_f;   off = k - C3; }
            float4 v = ((const float4*)src)[off];
            ushort4 o;
            o.x = f2bf(v.x); o.y = f2bf(v.y); o.z = f2bf(v.z); o.w = f2bf(v.w);
            ((ushort4*)dstb)[k] = o;
        }
    }
}

// ================= 128x128 bf16 MFMA GEMM tile (K=512), m97-style =================
__device__ __forceinline__ void gemm_tile_128(
    const unsigned short* __restrict__ A, int Arows,
    const unsigned short* __restrict__ B,
    const float* __restrict__ bias,
    float* __restrict__ C, int ldc,
    int bm, int bn)
{
    __shared__ short8 AsV[1024];   // 128 rows x 8 chunks (16B) = 16 KB
    __shared__ short8 BsV[1024];

    const int tid  = threadIdx.x;
    const int wave = tid >> 6;
    const int lane = tid & 63;
    const int quad = lane >> 4;
    const int lr   = lane & 15;
    const int wr = (wave >> 1) * 64;
    const int wc = (wave & 1) * 64;

    floatx4 acc[4][4];
    #pragma unroll
    for (int i = 0; i < 4; ++i)
        #pragma unroll
        for (int j = 0; j < 4; ++j)
            acc[i][j] = (floatx4){0.f, 0.f, 0.f, 0.f};

    int s_row[4], s_gk[4];
    #pragma unroll
    for (int it = 0; it < 4; ++it) {
        int c = it * 256 + wave * 64 + lane;
        s_row[it] = c >> 3;
        s_gk[it]  = (c & 7) ^ (s_row[it] & 7);
    }

    for (int k0 = 0; k0 < 512; k0 += 64) {
        #pragma unroll
        for (int it = 0; it < 4; ++it) {
            int row = s_row[it];
            int gm = bm + row; if (gm >= Arows) gm = Arows - 1;
            GLD_LDS(A + (size_t)gm * 512 + k0 + s_gk[it] * 8, &AsV[it * 256 + wave * 64]);
            int gn = bn + row;
            GLD_LDS(B + (size_t)gn * 512 + k0 + s_gk[it] * 8, &BsV[it * 256 + wave * 64]);
        }
        __syncthreads();

        #pragma unroll
        for (int kc = 0; kc < 2; ++kc) {
            short8 af[4], bfr[4];
            const int q = kc * 4 + quad;
            #pragma unroll
            for (int mt = 0; mt < 4; ++mt) {
                int row = wr + mt * 16 + lr;
                af[mt] = AsV[row * 8 + (q ^ (row & 7))];
            }
            #pragma unroll
            for (int nt = 0; nt < 4; ++nt) {
                int row = wc + nt * 16 + lr;
                bfr[nt] = BsV[row * 8 + (q ^ (row & 7))];
            }
            #pragma unroll
            for (int mt = 0; mt < 4; ++mt)
                #pragma unroll
                for (int nt = 0; nt < 4; ++nt)
                    acc[mt][nt] = __builtin_amdgcn_mfma_f32_16x16x32_bf16(
                        af[mt], bfr[nt], acc[mt][nt], 0, 0, 0);
        }
        __syncthreads();
    }

    #pragma unroll
    for (int mt = 0; mt < 4; ++mt) {
        #pragma unroll
        for (int r = 0; r < 4; ++r) {
            int gm = bm + wr + mt * 16 + quad * 4 + r;
            if (gm >= Arows) continue;
            #pragma unroll
            for (int nt = 0; nt < 4; ++nt) {
                int gn = bn + wc + nt * 16 + lr;
                float v = acc[mt][nt][r];
                if (bias) v += bias[gn];
                C[(size_t)gm * ldc + gn] = v;
            }
        }
    }
}

// ================= direct-from-global MFMA GEMM for tiny levels (no LDS, no barriers) ====
__device__ __forceinline__ void direct_tile_16x64(
    const unsigned short* __restrict__ A, int Arows,
    const unsigned short* __restrict__ B,
    float* __restrict__ C, int ldc,
    int m0, int n0)
{
    const int lane = threadIdx.x & 63;
    const int quad = lane >> 4;
    const int lr   = lane & 15;
    int am = m0 + lr; if (am >= Arows) am = Arows - 1;   // clamp (store-masked)
    const unsigned short* ap = A + (size_t)am * 512 + quad * 8;
    const unsigned short* bp = B + (size_t)(n0 + lr) * 512 + quad * 8;

    floatx4 acc[4];
    #pragma unroll
    for (int j = 0; j < 4; ++j) acc[j] = (floatx4){0.f, 0.f, 0.f, 0.f};

    #pragma unroll
    for (int k0 = 0; k0 < 512; k0 += 32) {
        short8 af = *(const short8*)(ap + k0);
        #pragma unroll
        for (int j = 0; j < 4; ++j) {
            short8 bf = *(const short8*)(bp + (size_t)j * 16 * 512 + k0);
            acc[j] = __builtin_amdgcn_mfma_f32_16x16x32_bf16(af, bf, acc[j], 0, 0, 0);
        }
    }

    #pragma unroll
    for (int j = 0; j < 4; ++j) {
        #pragma unroll
        for (int r = 0; r < 4; ++r) {
            int gm = m0 + quad * 4 + r;
            if (gm < Arows) C[(size_t)gm * ldc + n0 + j * 16 + lr] = acc[j][r];
        }
    }
}

// ================= small-level U-GEMMs phase (grid-stride over 16x64 wave tiles) ==========
__device__ __forceinline__ void small_gemm_phase(
    const unsigned short* __restrict__ hs_bf,
    const unsigned short* __restrict__ hch_bf,
    const unsigned short* __restrict__ Uib, const unsigned short* __restrict__ Ufb,
    float* __restrict__ ioud, float* __restrict__ fd, int nl)
{
    const int mI = (nl + 15) >> 4;
    const int mF = (4 * nl + 15) >> 4;
    const int totW = mI * 24 + mF * 8;
    for (int w = blockIdx.x * 4 + (threadIdx.x >> 6); w < totW; w += gridDim.x * 4) {
        if (w < mI * 24)
            direct_tile_16x64(hs_bf, nl, Uib, ioud, 1536, (w / 24) * 16, (w % 24) * 64);
        else {
            int w2 = w - mI * 24;
            direct_tile_16x64(hch_bf, 4 * nl, Ufb, fd, 512, (w2 / 8) * 16, (w2 % 8) * 64);
        }
    }
}

// ================= 256-thread combine: 4 siblings/parent group, 8 hid elems/thread ========
// thread: k = tid>>6 (sibling 0..3), jg = tid&63 -> elems [jg*8, jg*8+8)
__device__ void combine_level_256(
    const float* __restrict__ wx_iou, const float* __restrict__ wx_f,
    const float* __restrict__ ioud, const float* __restrict__ fd,
    const float* __restrict__ c_child,
    float* __restrict__ h_out, float* __restrict__ c_out,
    unsigned short* __restrict__ h_bf, unsigned short* __restrict__ hs_bf,
    int s, int np, int hasU)
{
    __shared__ floatx4 hsbuf[512];   // 8 KB
    const int k  = threadIdx.x >> 6;
    const int jg = threadIdx.x & 63;
    const int j8 = jg << 3;

    for (int tp = blockIdx.x; tp < np; tp += gridDim.x) {
        const int t = 4 * tp + k;
        const int n = s + t;
        const float* wrow = wx_iou + (size_t)n * 1536 + j8;
        floatx4 iv0 = *(const floatx4*)(wrow);
        floatx4 iv1 = *(const floatx4*)(wrow + 4);
        floatx4 ov0 = *(const floatx4*)(wrow + 512);
        floatx4 ov1 = *(const floatx4*)(wrow + 516);
        floatx4 uv0 = *(const floatx4*)(wrow + 1024);
        floatx4 uv1 = *(const floatx4*)(wrow + 1028);
        floatx4 fc0 = (floatx4){0.f,0.f,0.f,0.f};
        floatx4 fc1 = (floatx4){0.f,0.f,0.f,0.f};
        if (hasU) {
            const float* drow = ioud + (size_t)t * 1536 + j8;
            iv0 += *(const floatx4*)(drow);        iv1 += *(const floatx4*)(drow + 4);
            ov0 += *(const floatx4*)(drow + 512);  ov1 += *(const floatx4*)(drow + 516);
            uv0 += *(const floatx4*)(drow + 1024); uv1 += *(const floatx4*)(drow + 1028);
            const float* wfp = wx_f + (size_t)n * 512 + j8;
            floatx4 wf0 = *(const floatx4*)(wfp);
            floatx4 wf1 = *(const floatx4*)(wfp + 4);
            #pragma unroll
            for (int q = 0; q < 4; ++q) {
                const float* fp = fd + (size_t)(4 * t + q) * 512 + j8;
                const float* cp = c_child + (size_t)(4 * t + q) * 512 + j8;
                floatx4 f0 = *(const floatx4*)(fp),  f1 = *(const floatx4*)(fp + 4);
                floatx4 cv0 = *(const floatx4*)(cp), cv1 = *(const floatx4*)(cp + 4);
                fc0 += (wf0 + f0) * cv0;
                fc1 += (wf1 + f1) * cv1;
            }
        }
        floatx4 cn0, cn1, hn0, hn1;
        #pragma unroll
        for (int c = 0; c < 4; ++c) {
            float ig = 1.f / (1.f + expf(-iv0[c]));
            float og = 1.f / (1.f + expf(-ov0[c]));
            float ug = tanhf(uv0[c]);
            float cv2 = ig * ug + fc0[c];
            cn0[c] = cv2;
            hn0[c] = og * tanhf(cv2);
        }
        #pragma unroll
        for (int c = 0; c < 4; ++c) {
            float ig = 1.f / (1.f + expf(-iv1[c]));
            float og = 1.f / (1.f + expf(-ov1[c]));
            float ug = tanhf(uv1[c]);
            float cv2 = ig * ug + fc1[c];
            cn1[c] = cv2;
            hn1[c] = og * tanhf(cv2);
        }
        float* cop = c_out + (size_t)n * 512 + j8;
        float* hop = h_out + (size_t)n * 512 + j8;
        *(floatx4*)(cop)     = cn0;  *(floatx4*)(cop + 4) = cn1;
        *(floatx4*)(hop)     = hn0;  *(floatx4*)(hop + 4) = hn1;
        ushort4 hb0, hb1;
        hb0.x = f2bf(hn0[0]); hb0.y = f2bf(hn0[1]); hb0.z = f2bf(hn0[2]); hb0.w = f2bf(hn0[3]);
        hb1.x = f2bf(hn1[0]); hb1.y = f2bf(hn1[1]); hb1.z = f2bf(hn1[2]); hb1.w = f2bf(hn1[3]);
        *(ushort4*)(h_bf + (size_t)n * 512 + j8)     = hb0;
        *(ushort4*)(h_bf + (size_t)n * 512 + j8 + 4) = hb1;

        hsbuf[k * 128 + jg * 2]     = hn0;
        hsbuf[k * 128 + jg * 2 + 1] = hn1;
        __syncthreads();
        if (threadIdx.x < 64) {
            const int g = threadIdx.x;
            floatx4 s0 = hsbuf[g*2]   + hsbuf[128 + g*2]   + hsbuf[256 + g*2]   + hsbuf[384 + g*2];
            floatx4 s1 = hsbuf[g*2+1] + hsbuf[128 + g*2+1] + hsbuf[256 + g*2+1] + hsbuf[384 + g*2+1];
            ushort4 o0, o1;
            o0.x = f2bf(s0[0]); o0.y = f2bf(s0[1]); o0.z = f2bf(s0[2]); o0.w = f2bf(s0[3]);
            o1.x = f2bf(s1[0]); o1.y = f2bf(s1[1]); o1.z = f2bf(s1[2]); o1.w = f2bf(s1[3]);
            *(ushort4*)(hs_bf + (size_t)tp * 512 + g * 8)     = o0;
            *(ushort4*)(hs_bf + (size_t)tp * 512 + g * 8 + 4) = o1;
        }
        __syncthreads();
    }
}

// ======================================================================================
// MEGA KERNEL: all 15 phases in one cooperative launch, 14 grid.sync() barriers.
// Replaces 17 serially-dependent dispatches (~10 us launch floor each).
// ======================================================================================
__global__ __launch_bounds__(256, 2) void mega_kernel(
    const float* __restrict__ x,
    const float* __restrict__ W_iou, const float* __restrict__ b_iou,
    const float* __restrict__ W_f,   const float* __restrict__ b_f,
    const float* __restrict__ U_iou, const float* __restrict__ U_f,
    float* __restrict__ h_out, float* __restrict__ c_out,
    float* __restrict__ wx_iou, float* __restrict__ wx_f,
    float* __restrict__ ioud, float* __restrict__ fd,
    unsigned short* __restrict__ xb,
    unsigned short* __restrict__ Wib, unsigned short* __restrict__ Wfb,
    unsigned short* __restrict__ Uib, unsigned short* __restrict__ Ufb,
    unsigned short* __restrict__ h_bf, unsigned short* __restrict__ hs_bf)
{
    cg::grid_group grid = cg::this_grid();

    // ---- P0: prep (zero leaf h/c, cast x/W/U to bf16) ----
    prep_body(x, W_iou, W_f, U_iou, U_f,
              h_out + (size_t)N_INT * HID, c_out + (size_t)N_INT * HID, xb);
    grid.sync();

    // ---- P1: W-GEMMs: wx_iou (5461x1536) + wx_f (1365x512), 560 tile jobs ----
    for (int b = blockIdx.x; b < 560; b += gridDim.x) {
        if (b < 516)
            gemm_tile_128(xb, N_INT, Wib, b_iou, wx_iou, 1536, (b / 12) * 128, (b % 12) * 128);
        else {
            int b2 = b - 516;
            gemm_tile_128(xb, 1365, Wfb, b_f, wx_f, 512, (b2 / 4) * 128, (b2 % 4) * 128);
        }
    }
    grid.sync();

    // ---- P2: combine level 6 (children are leaves, no U terms) ----
    combine_level_256(wx_iou, nullptr, nullptr, nullptr, nullptr,
                      h_out, c_out, h_bf, hs_bf, 1365, 1024, 0);
    grid.sync();

    // ---- P3: level-5 U-GEMMs (224 tile jobs) ----
    for (int b = blockIdx.x; b < 224; b += gridDim.x) {
        if (b < 96)
            gemm_tile_128(hs_bf, 1024, Uib, nullptr, ioud, 1536, (b / 12) * 128, (b % 12) * 128);
        else {
            int b2 = b - 96;
            gemm_tile_128(h_bf + (size_t)1365 * HID, 4096, Ufb, nullptr, fd, 512,
                          (b2 / 4) * 128, (b2 % 4) * 128);
        }
    }
    grid.sync();

    // ---- P4: combine level 5 ----
    combine_level_256(wx_iou, wx_f, ioud, fd, c_out + (size_t)1365 * HID,
                      h_out, c_out, h_bf, hs_bf, 341, 256, 1);
    grid.sync();

    // ---- P5: level-4 U-GEMMs (56 tile jobs) ----
    for (int b = blockIdx.x; b < 56; b += gridDim.x) {
        if (b < 24)
            gemm_tile_128(hs_bf, 256, Uib, nullptr, ioud, 1536, (b / 12) * 128, (b % 12) * 128);
        else {
            int b2 = b - 24;
            gemm_tile_128(h_bf + (size_t)341 * HID, 1024, Ufb, nullptr, fd, 512,
                          (b2 / 4) * 128, (b2 % 4) * 128);
        }
    }
    grid.sync();

    // ---- P6: combine level 4 ----
    combine_level_256(wx_iou, wx_f, ioud, fd, c_out + (size_t)341 * HID,
                      h_out, c_out, h_bf, hs_bf, 85, 64, 1);
    grid.sync();

    // ---- P7..P12: levels 3..1 (direct-load GEMM + combine) ----
    // level 3: s=21 nl=64 cb=85
    small_gemm_phase(hs_bf, h_bf + (size_t)85 * HID, Uib, Ufb, ioud, fd, 64);
    grid.sync();
    combine_level_256(wx_iou, wx_f, ioud, fd, c_out + (size_t)85 * HID,
                      h_out, c_out, h_bf, hs_bf, 21, 16, 1);
    grid.sync();
    // level 2: s=5 nl=16 cb=21
    small_gemm_phase(hs_bf, h_bf + (size_t)21 * HID, Uib, Ufb, ioud, fd, 16);
    grid.sync();
    combine_level_256(wx_iou, wx_f, ioud, fd, c_out + (size_t)21 * HID,
                      h_out, c_out, h_bf, hs_bf, 5, 4, 1);
    grid.sync();
    // level 1: s=1 nl=4 cb=5
    small_gemm_phase(hs_bf, h_bf + (size_t)5 * HID, Uib, Ufb, ioud, fd, 4);
    grid.sync();
    combine_level_256(wx_iou, wx_f, ioud, fd, c_out + (size_t)5 * HID,
                      h_out, c_out, h_bf, hs_bf, 1, 1, 1);
    grid.sync();

    // ---- P13: root U-GEMMs (nl = 1) ----
    small_gemm_phase(hs_bf, h_bf + (size_t)1 * HID, Uib, Ufb, ioud, fd, 1);
    grid.sync();

    // ---- P14: root combine (node 0) — block 0 only, no barrier after ----
    if (blockIdx.x == 0) {
        const int j = threadIdx.x * 2;
        #pragma unroll
        for (int c = 0; c < 2; ++c) {
            const int jj = j + c;
            float iv = wx_iou[jj]        + ioud[jj];
            float ov = wx_iou[512 + jj]  + ioud[512 + jj];
            float uv = wx_iou[1024 + jj] + ioud[1024 + jj];
            float wf = wx_f[jj];
            float fc = 0.f;
            #pragma unroll
            for (int q = 0; q < 4; ++q)
                fc += (wf + fd[(size_t)q * 512 + jj]) * c_out[(size_t)(q + 1) * 512 + jj];
            float ig = 1.f / (1.f + expf(-iv));
            float og = 1.f / (1.f + expf(-ov));
            float ug = tanhf(uv);
            float cv2 = ig * ug + fc;
            c_out[jj] = cv2;
            h_out[jj] = og * tanhf(cv2);
        }
    }
}

// ======================================================================================
// Fallback multi-dispatch path (previous verified 275 us version), used only if the
// cooperative launch is unavailable.
// ======================================================================================
__global__ void prep_kernel(const float* __restrict__ x,
                            const float* __restrict__ W_iou,
                            const float* __restrict__ W_f,
                            const float* __restrict__ U_iou,
                            const float* __restrict__ U_f,
                            float* __restrict__ h_leaf,
                            float* __restrict__ c_leaf,
                            unsigned short* __restrict__ dstb)
{
    prep_body(x, W_iou, W_f, U_iou, U_f, h_leaf, c_leaf, dstb);
}

__global__ __launch_bounds__(256) void wgemm_kernel(
    const unsigned short* __restrict__ xb,
    const unsigned short* __restrict__ Wib,
    const unsigned short* __restrict__ Wfb,
    const float* __restrict__ b_iou, const float* __restrict__ b_f,
    float* __restrict__ wx_iou, float* __restrict__ wx_f)
{
    int b = blockIdx.x;
    if (b < 516) {
        gemm_tile_128(xb, N_INT, Wib, b_iou, wx_iou, 1536, (b / 12) * 128, (b % 12) * 128);
    } else {
        int b2 = b - 516;
        gemm_tile_128(xb, 1365, Wfb, b_f, wx_f, 512, (b2 / 4) * 128, (b2 % 4) * 128);
    }
}

__global__ __launch_bounds__(256) void gemm5_kernel(
    const unsigned short* __restrict__ hs_bf,
    const unsigned short* __restrict__ h6_bf,
    const unsigned short* __restrict__ Uib, const unsigned short* __restrict__ Ufb,
    float* __restrict__ ioud, float* __restrict__ fd)
{
    int b = blockIdx.x;
    if (b < 96) {
        gemm_tile_128(hs_bf, 1024, Uib, nullptr, ioud, 1536, (b / 12) * 128, (b % 12) * 128);
    } else {
        int b2 = b - 96;
        gemm_tile_128(h6_bf, 4096, Ufb, nullptr, fd, 512, (b2 / 4) * 128, (b2 % 4) * 128);
    }
}

__global__ __launch_bounds__(256) void gemm4_kernel(
    const unsigned short* __restrict__ hs_bf,
    const unsigned short* __restrict__ h5_bf,
    const unsigned short* __restrict__ Uib, const unsigned short* __restrict__ Ufb,
    float* __restrict__ ioud, float* __restrict__ fd)
{
    int b = blockIdx.x;
    if (b < 24) {
        gemm_tile_128(hs_bf, 256, Uib, nullptr, ioud, 1536, (b / 12) * 128, (b % 12) * 128);
    } else {
        int b2 = b - 24;
        gemm_tile_128(h5_bf, 1024, Ufb, nullptr, fd, 512, (b2 / 4) * 128, (b2 % 4) * 128);
    }
}

__global__ __launch_bounds__(256) void gemm_small_kernel(
    const unsigned short* __restrict__ hs_bf,
    const unsigned short* __restrict__ hch_bf,
    const unsigned short* __restrict__ Uib, const unsigned short* __restrict__ Ufb,
    float* __restrict__ ioud, float* __restrict__ fd, int nl)
{
    const int w = blockIdx.x * 4 + (threadIdx.x >> 6);
    const int mI = (nl + 15) >> 4;
    const int mF = (4 * nl + 15) >> 4;
    if (w < mI * 24) {
        direct_tile_16x64(hs_bf, nl, Uib, ioud, 1536, (w / 24) * 16, (w % 24) * 64);
    } else {
        int w2 = w - mI * 24;
        if (w2 < mF * 8)
            direct_tile_16x64(hch_bf, 4 * nl, Ufb, fd, 512, (w2 / 8) * 16, (w2 % 8) * 64);
    }
}

__global__ __launch_bounds__(256) void combine_kernel_fb(
    const float* __restrict__ wx_iou, const float* __restrict__ wx_f,
    const float* __restrict__ ioud, const float* __restrict__ fd,
    const float* __restrict__ c_child,
    float* __restrict__ h_out, float* __restrict__ c_out,
    unsigned short* __restrict__ h_bf, unsigned short* __restrict__ hs_bf,
    int s, int np, int hasU)
{
    combine_level_256(wx_iou, wx_f, ioud, fd, c_child, h_out, c_out, h_bf, hs_bf, s, np, hasU);
}

__global__ __launch_bounds__(128) void combine_root_kernel(
    const float* __restrict__ wx_iou, const float* __restrict__ wx_f,
    const float* __restrict__ ioud, const float* __restrict__ fd,
    const float* __restrict__ c_child,
    float* __restrict__ h_out, float* __restrict__ c_out)
{
    const int j4 = threadIdx.x << 2;
    #pragma unroll
    for (int c = 0; c < 4; ++c) {
        const int jj = j4 + c;
        float iv = wx_iou[jj]        + ioud[jj];
        float ov = wx_iou[512 + jj]  + ioud[512 + jj];
        float uv = wx_iou[1024 + jj] + ioud[1024 + jj];
        float wf = wx_f[jj];
        float fc = 0.f;
        #pragma unroll
        for (int q = 0; q < 4; ++q)
            fc += (wf + fd[(size_t)q * 512 + jj]) * c_child[(size_t)q * 512 + jj];
        float ig = 1.f / (1.f + expf(-iv));
        float og = 1.f / (1.f + expf(-ov));
        float ug = tanhf(uv);
        float cv2 = ig * ug + fc;
        c_out[jj] = cv2;
        h_out[jj] = og * tanhf(cv2);
    }
}

extern "C" void kernel_launch(void* const* d_in, const int* in_sizes, int n_in,
                              void* d_out, int out_size, void* d_ws, size_t ws_size,
                              hipStream_t stream) {
    const float* x     = (const float*)d_in[0];
    // d_in[1] = children: deterministic (4n+1..4n+4), not needed
    const float* W_iou = (const float*)d_in[2];
    const float* b_iou = (const float*)d_in[3];
    const float* W_f   = (const float*)d_in[4];
    const float* b_f   = (const float*)d_in[5];
    const float* U_iou = (const float*)d_in[6];
    const float* U_f   = (const float*)d_in[7];

    float* h_out = (float*)d_out;                       // N_NODES x 512
    float* c_out = h_out + (size_t)N_NODES * HID;       // N_NODES x 512

    // ---- workspace layout (fp32 region, then contiguous bf16 cast region) ----
    float* ws     = (float*)d_ws;
    float* wx_iou = ws;                                  // 5461*1536 f32
    float* wx_f   = wx_iou + (size_t)N_INT * 1536;       // 1365*512  f32
    float* ioud   = wx_f   + (size_t)1365 * 512;         // 1024*1536 f32
    float* fd     = ioud   + (size_t)1024 * 1536;        // 4096*512  f32
    unsigned short* xb   = (unsigned short*)(fd + (size_t)4096 * 512);
    unsigned short* Wib  = xb  + (size_t)N_INT * 512;    // 1536*512 bf16
    unsigned short* Wfb  = Wib + (size_t)1536 * 512;     // 512*512
    unsigned short* Uib  = Wfb + (size_t)512 * 512;      // 1536*512
    unsigned short* Ufb  = Uib + (size_t)1536 * 512;     // 512*512
    unsigned short* h_bf = Ufb + (size_t)512 * 512;      // 5461*512
    unsigned short* hs_bf= h_bf + (size_t)N_INT * 512;   // 1024*512

    // ---- cooperative mega-kernel path ----
    static int coopGrid = -1;   // -1 unknown, 0 disabled, >0 grid size
    if (coopGrid == -1) {
        int nb = 0;
        hipError_t qe = hipOccupancyMaxActiveBlocksPerMultiprocessor(&nb, mega_kernel, 256, 0);
        if (qe == hipSuccess && nb >= 1) {
            if (nb > 3) nb = 3;              // cap grid (barrier cost) at 768 blocks
            coopGrid = nb * 256;
        } else {
            coopGrid = 0;
            (void)hipGetLastError();
        }
    }

    bool launched = false;
    if (coopGrid > 0) {
        void* args[] = { (void*)&x, (void*)&W_iou, (void*)&b_iou, (void*)&W_f, (void*)&b_f,
                         (void*)&U_iou, (void*)&U_f, (void*)&h_out, (void*)&c_out,
                         (void*)&wx_iou, (void*)&wx_f, (void*)&ioud, (void*)&fd,
                         (void*)&xb, (void*)&Wib, (void*)&Wfb, (void*)&Uib, (void*)&Ufb,
                         (void*)&h_bf, (void*)&hs_bf };
        hipError_t e = hipLaunchCooperativeKernel((const void*)mega_kernel,
                                                  dim3(coopGrid), dim3(256), args, 0, stream);
        if (e == hipSuccess) {
            launched = true;
        } else {
            coopGrid = 0;                    // never retry; fall through to old path
            (void)hipGetLastError();
        }
    }

    if (!launched) {
        // ---- previous verified 17-dispatch path ----
        prep_kernel<<<2048, 256, 0, stream>>>(x, W_iou, W_f, U_iou, U_f,
                                              h_out + (size_t)N_INT * HID,
                                              c_out + (size_t)N_INT * HID, xb);
        wgemm_kernel<<<516 + 44, 256, 0, stream>>>(xb, Wib, Wfb, b_iou, b_f, wx_iou, wx_f);
        combine_kernel_fb<<<1024, 256, 0, stream>>>(
            wx_iou, nullptr, nullptr, nullptr, nullptr,
            h_out, c_out, h_bf, hs_bf, 1365, 1024, 0);
        gemm5_kernel<<<224, 256, 0, stream>>>(hs_bf, h_bf + (size_t)1365 * HID, Uib, Ufb, ioud, fd);
        combine_kernel_fb<<<256, 256, 0, stream>>>(
            wx_iou, wx_f, ioud, fd, c_out + (size_t)1365 * HID,
            h_out, c_out, h_bf, hs_bf, 341, 256, 1);
        gemm4_kernel<<<56, 256, 0, stream>>>(hs_bf, h_bf + (size_t)341 * HID, Uib, Ufb, ioud, fd);
        combine_kernel_fb<<<64, 256, 0, stream>>>(
            wx_iou, wx_f, ioud, fd, c_out + (size_t)341 * HID,
            h_out, c_out, h_bf, hs_bf, 85, 64, 1);
        const int offs[9] = {0, 1, 5, 21, 85, 341, 1365, 5461, 21845};
        for (int l = 3; l >= 1; --l) {
            const int s  = offs[l];
            const int nl = offs[l + 1] - s;
            const int cb = offs[l + 1];
            const int mI = (nl + 15) >> 4;
            const int mF = (4 * nl + 15) >> 4;
            const int waves = mI * 24 + mF * 8;
            gemm_small_kernel<<<(waves + 3) / 4, 256, 0, stream>>>(
                hs_bf, h_bf + (size_t)cb * HID, Uib, Ufb, ioud, fd, nl);
            combine_kernel_fb<<<(nl + 3) / 4, 256, 0, stream>>>(
                wx_iou, wx_f, ioud, fd, c_out + (size_t)cb * HID,
                h_out, c_out, h_bf, hs_bf, s, nl >> 2, 1);
        }
        gemm_small_kernel<<<8, 256, 0, stream>>>(
            hs_bf, h_bf + (size_t)1 * HID, Uib, Ufb, ioud, fd, 1);
        combine_root_kernel<<<1, 128, 0, stream>>>(
            wx_iou, wx_f, ioud, fd, c_out + (size_t)1 * HID, h_out, c_out);
    }
}

// Round 2
// 499.820 us; speedup vs baseline: 1.4093x; 1.4093x over previous
//
#include <hip/hip_runtime.h>
#include <cmath>

// Tree constants (complete 4-ary tree, depth 7)
constexpr int N_NODES = 21845;
constexpr int N_INT   = 5461;   // internal nodes (levels 0..6)
constexpr int HID     = 512;

typedef short  short8  __attribute__((ext_vector_type(8)));
typedef float  floatx4 __attribute__((ext_vector_type(4)));

// fp32 -> bf16 bit pattern, round-to-nearest-even
__device__ __forceinline__ unsigned short f2bf(float f) {
    unsigned int u = __float_as_uint(f);
    u += 0x7fffu + ((u >> 16) & 1u);
    return (unsigned short)(u >> 16);
}

#define GLD_LDS(g, l) __builtin_amdgcn_global_load_lds( \
    (const __attribute__((address_space(1))) void*)(g), \
    (__attribute__((address_space(3))) void*)(l), 16, 0, 0)

// ================= custom fast grid barrier =================
// cg::grid_group::sync() measured ~57 us/sync on gfx950 (round-1: 14 syncs = ~800 us idle).
// This is a phase-counter barrier: 1 agent-scope RMW arrival per block (release),
// relaxed agent-scope polling (bypasses L1/L2, sees remote updates), acquire fence on exit.
// __syncthreads() before arrival drains vmcnt per wave -> block's writes are in L2;
// the release RMW writes back the XCD L2; the acquire fence invalidates L1/L2.
__device__ __forceinline__ void grid_bar(unsigned* cnt, unsigned phase) {
    __syncthreads();
    if (threadIdx.x == 0) {
        const unsigned target = gridDim.x * phase;
        __hip_atomic_fetch_add(cnt, 1u, __ATOMIC_RELEASE, __HIP_MEMORY_SCOPE_AGENT);
        while (__hip_atomic_load(cnt, __ATOMIC_RELAXED, __HIP_MEMORY_SCOPE_AGENT) < target)
            __builtin_amdgcn_s_sleep(1);
        __builtin_amdgcn_fence(__ATOMIC_ACQUIRE, "agent");
    }
    __syncthreads();
}

// ================= prep body (fallback path only): zero leaf h/c + cast all operands =====
__device__ __forceinline__ void prep_body(const float* __restrict__ x,
                                          const float* __restrict__ W_iou,
                                          const float* __restrict__ W_f,
                                          const float* __restrict__ U_iou,
                                          const float* __restrict__ U_f,
                                          float* __restrict__ h_leaf,
                                          float* __restrict__ c_leaf,
                                          unsigned short* __restrict__ dstb)
{
    const size_t Z  = (size_t)(N_NODES - N_INT) * HID / 4;
    const size_t C0 = (size_t)N_INT * 512 / 4;
    const size_t C1 = C0 + 1536 * 512 / 4;
    const size_t C2 = C1 + 512 * 512 / 4;
    const size_t C3 = C2 + 1536 * 512 / 4;
    const size_t C4 = C3 + 512 * 512 / 4;
    const size_t total = 2 * Z + C4;
    size_t i = (size_t)blockIdx.x * blockDim.x + threadIdx.x;
    const size_t stride = (size_t)gridDim.x * blockDim.x;
    const float4 zz = {0.f, 0.f, 0.f, 0.f};
    for (; i < total; i += stride) {
        if (i < 2 * Z) {
            if (i < Z) ((float4*)h_leaf)[i] = zz;
            else       ((float4*)c_leaf)[i - Z] = zz;
        } else {
            size_t k = i - 2 * Z;
            const float* src; size_t off;
            if (k < C0)      { src = x;     off = k; }
            else if (k < C1) { src = W_iou; off = k - C0; }
            else if (k < C2) { src = W_f;   off = k - C1; }
            else if (k < C3) { src = U_iou; off = k - C2; }
            else             { src = U_f;   off = k - C3; }
            float4 v = ((const float4*)src)[off];
            ushort4 o;
            o.x = f2bf(v.x); o.y = f2bf(v.y); o.z = f2bf(v.z); o.w = f2bf(v.w);
            ((ushort4*)dstb)[k] = o;
        }
    }
}

// ================= 128x128 bf16 MFMA GEMM tile (K=512), m97-style =================
__device__ __forceinline__ void gemm_tile_128(
    const unsigned short* __restrict__ A, int Arows,
    const unsigned short* __restrict__ B,
    const float* __restrict__ bias,
    float* __restrict__ C, int ldc,
    int bm, int bn)
{
    __shared__ short8 AsV[1024];   // 128 rows x 8 chunks (16B) = 16 KB
    __shared__ short8 BsV[1024];

    const int tid  = threadIdx.x;
    const int wave = tid >> 6;
    const int lane = tid & 63;
    const int quad = lane >> 4;
    const int lr   = lane & 15;
    const int wr = (wave >> 1) * 64;
    const int wc = (wave & 1) * 64;

    floatx4 acc[4][4];
    #pragma unroll
    for (int i = 0; i < 4; ++i)
        #pragma unroll
        for (int j = 0; j < 4; ++j)
            acc[i][j] = (floatx4){0.f, 0.f, 0.f, 0.f};

    int s_row[4], s_gk[4];
    #pragma unroll
    for (int it = 0; it < 4; ++it) {
        int c = it * 256 + wave * 64 + lane;
        s_row[it] = c >> 3;
        s_gk[it]  = (c & 7) ^ (s_row[it] & 7);
    }

    for (int k0 = 0; k0 < 512; k0 += 64) {
        #pragma unroll
        for (int it = 0; it < 4; ++it) {
            int row = s_row[it];
            int gm = bm + row; if (gm >= Arows) gm = Arows - 1;
            GLD_LDS(A + (size_t)gm * 512 + k0 + s_gk[it] * 8, &AsV[it * 256 + wave * 64]);
            int gn = bn + row;
            GLD_LDS(B + (size_t)gn * 512 + k0 + s_gk[it] * 8, &BsV[it * 256 + wave * 64]);
        }
        __syncthreads();

        #pragma unroll
        for (int kc = 0; kc < 2; ++kc) {
            short8 af[4], bfr[4];
            const int q = kc * 4 + quad;
            #pragma unroll
            for (int mt = 0; mt < 4; ++mt) {
                int row = wr + mt * 16 + lr;
                af[mt] = AsV[row * 8 + (q ^ (row & 7))];
            }
            #pragma unroll
            for (int nt = 0; nt < 4; ++nt) {
                int row = wc + nt * 16 + lr;
                bfr[nt] = BsV[row * 8 + (q ^ (row & 7))];
            }
            #pragma unroll
            for (int mt = 0; mt < 4; ++mt)
                #pragma unroll
                for (int nt = 0; nt < 4; ++nt)
                    acc[mt][nt] = __builtin_amdgcn_mfma_f32_16x16x32_bf16(
                        af[mt], bfr[nt], acc[mt][nt], 0, 0, 0);
        }
        __syncthreads();
    }

    #pragma unroll
    for (int mt = 0; mt < 4; ++mt) {
        #pragma unroll
        for (int r = 0; r < 4; ++r) {
            int gm = bm + wr + mt * 16 + quad * 4 + r;
            if (gm >= Arows) continue;
            #pragma unroll
            for (int nt = 0; nt < 4; ++nt) {
                int gn = bn + wc + nt * 16 + lr;
                float v = acc[mt][nt][r];
                if (bias) v += bias[gn];
                C[(size_t)gm * ldc + gn] = v;
            }
        }
    }
}

// ================= direct-from-global MFMA GEMM for tiny levels (no LDS, no barriers) ====
__device__ __forceinline__ void direct_tile_16x64(
    const unsigned short* __restrict__ A, int Arows,
    const unsigned short* __restrict__ B,
    float* __restrict__ C, int ldc,
    int m0, int n0)
{
    const int lane = threadIdx.x & 63;
    const int quad = lane >> 4;
    const int lr   = lane & 15;
    int am = m0 + lr; if (am >= Arows) am = Arows - 1;   // clamp (store-masked)
    const unsigned short* ap = A + (size_t)am * 512 + quad * 8;
    const unsigned short* bp = B + (size_t)(n0 + lr) * 512 + quad * 8;

    floatx4 acc[4];
    #pragma unroll
    for (int j = 0; j < 4; ++j) acc[j] = (floatx4){0.f, 0.f, 0.f, 0.f};

    #pragma unroll
    for (int k0 = 0; k0 < 512; k0 += 32) {
        short8 af = *(const short8*)(ap + k0);
        #pragma unroll
        for (int j = 0; j < 4; ++j) {
            short8 bf = *(const short8*)(bp + (size_t)j * 16 * 512 + k0);
            acc[j] = __builtin_amdgcn_mfma_f32_16x16x32_bf16(af, bf, acc[j], 0, 0, 0);
        }
    }

    #pragma unroll
    for (int j = 0; j < 4; ++j) {
        #pragma unroll
        for (int r = 0; r < 4; ++r) {
            int gm = m0 + quad * 4 + r;
            if (gm < Arows) C[(size_t)gm * ldc + n0 + j * 16 + lr] = acc[j][r];
        }
    }
}

// ================= small-level U-GEMMs phase (grid-stride over 16x64 wave tiles) ==========
__device__ __forceinline__ void small_gemm_phase(
    const unsigned short* __restrict__ hs_bf,
    const unsigned short* __restrict__ hch_bf,
    const unsigned short* __restrict__ Uib, const unsigned short* __restrict__ Ufb,
    float* __restrict__ ioud, float* __restrict__ fd, int nl)
{
    const int mI = (nl + 15) >> 4;
    const int mF = (4 * nl + 15) >> 4;
    const int totW = mI * 24 + mF * 8;
    for (int w = blockIdx.x * 4 + (threadIdx.x >> 6); w < totW; w += gridDim.x * 4) {
        if (w < mI * 24)
            direct_tile_16x64(hs_bf, nl, Uib, ioud, 1536, (w / 24) * 16, (w % 24) * 64);
        else {
            int w2 = w - mI * 24;
            direct_tile_16x64(hch_bf, 4 * nl, Ufb, fd, 512, (w2 / 8) * 16, (w2 % 8) * 64);
        }
    }
}

// ================= 256-thread combine: 4 siblings/parent group, 8 hid elems/thread ========
__device__ void combine_level_256(
    const float* __restrict__ wx_iou, const float* __restrict__ wx_f,
    const float* __restrict__ ioud, const float* __restrict__ fd,
    const float* __restrict__ c_child,
    float* __restrict__ h_out, float* __restrict__ c_out,
    unsigned short* __restrict__ h_bf, unsigned short* __restrict__ hs_bf,
    int s, int np, int hasU)
{
    __shared__ floatx4 hsbuf[512];   // 8 KB
    const int k  = threadIdx.x >> 6;
    const int jg = threadIdx.x & 63;
    const int j8 = jg << 3;

    for (int tp = blockIdx.x; tp < np; tp += gridDim.x) {
        const int t = 4 * tp + k;
        const int n = s + t;
        const float* wrow = wx_iou + (size_t)n * 1536 + j8;
        floatx4 iv0 = *(const floatx4*)(wrow);
        floatx4 iv1 = *(const floatx4*)(wrow + 4);
        floatx4 ov0 = *(const floatx4*)(wrow + 512);
        floatx4 ov1 = *(const floatx4*)(wrow + 516);
        floatx4 uv0 = *(const floatx4*)(wrow + 1024);
        floatx4 uv1 = *(const floatx4*)(wrow + 1028);
        floatx4 fc0 = (floatx4){0.f,0.f,0.f,0.f};
        floatx4 fc1 = (floatx4){0.f,0.f,0.f,0.f};
        if (hasU) {
            const float* drow = ioud + (size_t)t * 1536 + j8;
            iv0 += *(const floatx4*)(drow);        iv1 += *(const floatx4*)(drow + 4);
            ov0 += *(const floatx4*)(drow + 512);  ov1 += *(const floatx4*)(drow + 516);
            uv0 += *(const floatx4*)(drow + 1024); uv1 += *(const floatx4*)(drow + 1028);
            const float* wfp = wx_f + (size_t)n * 512 + j8;
            floatx4 wf0 = *(const floatx4*)(wfp);
            floatx4 wf1 = *(const floatx4*)(wfp + 4);
            #pragma unroll
            for (int q = 0; q < 4; ++q) {
                const float* fp = fd + (size_t)(4 * t + q) * 512 + j8;
                const float* cp = c_child + (size_t)(4 * t + q) * 512 + j8;
                floatx4 f0 = *(const floatx4*)(fp),  f1 = *(const floatx4*)(fp + 4);
                floatx4 cv0 = *(const floatx4*)(cp), cv1 = *(const floatx4*)(cp + 4);
                fc0 += (wf0 + f0) * cv0;
                fc1 += (wf1 + f1) * cv1;
            }
        }
        floatx4 cn0, cn1, hn0, hn1;
        #pragma unroll
        for (int c = 0; c < 4; ++c) {
            float ig = 1.f / (1.f + expf(-iv0[c]));
            float og = 1.f / (1.f + expf(-ov0[c]));
            float ug = tanhf(uv0[c]);
            float cv2 = ig * ug + fc0[c];
            cn0[c] = cv2;
            hn0[c] = og * tanhf(cv2);
        }
        #pragma unroll
        for (int c = 0; c < 4; ++c) {
            float ig = 1.f / (1.f + expf(-iv1[c]));
            float og = 1.f / (1.f + expf(-ov1[c]));
            float ug = tanhf(uv1[c]);
            float cv2 = ig * ug + fc1[c];
            cn1[c] = cv2;
            hn1[c] = og * tanhf(cv2);
        }
        float* cop = c_out + (size_t)n * 512 + j8;
        float* hop = h_out + (size_t)n * 512 + j8;
        *(floatx4*)(cop)     = cn0;  *(floatx4*)(cop + 4) = cn1;
        *(floatx4*)(hop)     = hn0;  *(floatx4*)(hop + 4) = hn1;
        ushort4 hb0, hb1;
        hb0.x = f2bf(hn0[0]); hb0.y = f2bf(hn0[1]); hb0.z = f2bf(hn0[2]); hb0.w = f2bf(hn0[3]);
        hb1.x = f2bf(hn1[0]); hb1.y = f2bf(hn1[1]); hb1.z = f2bf(hn1[2]); hb1.w = f2bf(hn1[3]);
        *(ushort4*)(h_bf + (size_t)n * 512 + j8)     = hb0;
        *(ushort4*)(h_bf + (size_t)n * 512 + j8 + 4) = hb1;

        hsbuf[k * 128 + jg * 2]     = hn0;
        hsbuf[k * 128 + jg * 2 + 1] = hn1;
        __syncthreads();
        if (threadIdx.x < 64) {
            const int g = threadIdx.x;
            floatx4 s0 = hsbuf[g*2]   + hsbuf[128 + g*2]   + hsbuf[256 + g*2]   + hsbuf[384 + g*2];
            floatx4 s1 = hsbuf[g*2+1] + hsbuf[128 + g*2+1] + hsbuf[256 + g*2+1] + hsbuf[384 + g*2+1];
            ushort4 o0, o1;
            o0.x = f2bf(s0[0]); o0.y = f2bf(s0[1]); o0.z = f2bf(s0[2]); o0.w = f2bf(s0[3]);
            o1.x = f2bf(s1[0]); o1.y = f2bf(s1[1]); o1.z = f2bf(s1[2]); o1.w = f2bf(s1[3]);
            *(ushort4*)(hs_bf + (size_t)tp * 512 + g * 8)     = o0;
            *(ushort4*)(hs_bf + (size_t)tp * 512 + g * 8 + 4) = o1;
        }
        __syncthreads();
    }
}

// ======================================================================================
// MEGA KERNEL v2: all phases in one cooperative launch, 14 CUSTOM barriers.
// vs round-1: cg::grid_group::sync() (~57 us each) replaced by grid_bar (~4-6 us each).
// Leaf h/c zeroing moved to the tail (no consumer; overlaps root combine).
// U_iou/U_f casts moved into P1's idle blocks (only needed at P3).
// ======================================================================================
__global__ __launch_bounds__(256, 2) void mega_kernel(
    const float* __restrict__ x,
    const float* __restrict__ W_iou, const float* __restrict__ b_iou,
    const float* __restrict__ W_f,   const float* __restrict__ b_f,
    const float* __restrict__ U_iou, const float* __restrict__ U_f,
    float* __restrict__ h_out, float* __restrict__ c_out,
    float* __restrict__ wx_iou, float* __restrict__ wx_f,
    float* __restrict__ ioud, float* __restrict__ fd,
    unsigned short* __restrict__ xb,
    unsigned short* __restrict__ Wib, unsigned short* __restrict__ Wfb,
    unsigned short* __restrict__ Uib, unsigned short* __restrict__ Ufb,
    unsigned short* __restrict__ h_bf, unsigned short* __restrict__ hs_bf,
    unsigned* bar)
{
    const size_t NB  = gridDim.x;
    const size_t tid0 = (size_t)blockIdx.x * 256 + threadIdx.x;
    const size_t gstr = NB * 256;

    // ---- P0: cast xb / Wib / Wfb (only operands P1 needs) ----
    {
        const size_t C0 = (size_t)N_INT * 512 / 4;
        const size_t C1 = C0 + 1536 * 512 / 4;
        const size_t C2 = C1 + 512 * 512 / 4;
        for (size_t k = tid0; k < C2; k += gstr) {
            const float* src; size_t off;
            if (k < C0)      { src = x;     off = k; }
            else if (k < C1) { src = W_iou; off = k - C0; }
            else             { src = W_f;   off = k - C1; }
            float4 v = ((const float4*)src)[off];
            ushort4 o;
            o.x = f2bf(v.x); o.y = f2bf(v.y); o.z = f2bf(v.z); o.w = f2bf(v.w);
            ((ushort4*)xb)[k] = o;
        }
    }
    grid_bar(bar, 1);

    // ---- P1: W-GEMMs (560 tile jobs) + U_iou/U_f casts on spare cycles ----
    for (int b = blockIdx.x; b < 560; b += (int)NB) {
        if (b < 516)
            gemm_tile_128(xb, N_INT, Wib, b_iou, wx_iou, 1536, (b / 12) * 128, (b % 12) * 128);
        else {
            int b2 = b - 516;
            gemm_tile_128(xb, 1365, Wfb, b_f, wx_f, 512, (b2 / 4) * 128, (b2 % 4) * 128);
        }
    }
    {
        const size_t CU0 = 1536 * 512 / 4;
        const size_t CU1 = CU0 + 512 * 512 / 4;
        for (size_t k = tid0; k < CU1; k += gstr) {
            const float* src = (k < CU0) ? U_iou : U_f;
            size_t off = (k < CU0) ? k : k - CU0;
            float4 v = ((const float4*)src)[off];
            ushort4 o;
            o.x = f2bf(v.x); o.y = f2bf(v.y); o.z = f2bf(v.z); o.w = f2bf(v.w);
            ((ushort4*)Uib)[k] = o;
        }
    }
    grid_bar(bar, 2);

    // ---- P2: combine level 6 (children are leaves, no U terms) ----
    combine_level_256(wx_iou, nullptr, nullptr, nullptr, nullptr,
                      h_out, c_out, h_bf, hs_bf, 1365, 1024, 0);
    grid_bar(bar, 3);

    // ---- P3: level-5 U-GEMMs (224 tile jobs) ----
    for (int b = blockIdx.x; b < 224; b += (int)NB) {
        if (b < 96)
            gemm_tile_128(hs_bf, 1024, Uib, nullptr, ioud, 1536, (b / 12) * 128, (b % 12) * 128);
        else {
            int b2 = b - 96;
            gemm_tile_128(h_bf + (size_t)1365 * HID, 4096, Ufb, nullptr, fd, 512,
                          (b2 / 4) * 128, (b2 % 4) * 128);
        }
    }
    grid_bar(bar, 4);

    // ---- P4: combine level 5 ----
    combine_level_256(wx_iou, wx_f, ioud, fd, c_out + (size_t)1365 * HID,
                      h_out, c_out, h_bf, hs_bf, 341, 256, 1);
    grid_bar(bar, 5);

    // ---- P5: level-4 U-GEMMs (56 tile jobs) ----
    for (int b = blockIdx.x; b < 56; b += (int)NB) {
        if (b < 24)
            gemm_tile_128(hs_bf, 256, Uib, nullptr, ioud, 1536, (b / 12) * 128, (b % 12) * 128);
        else {
            int b2 = b - 24;
            gemm_tile_128(h_bf + (size_t)341 * HID, 1024, Ufb, nullptr, fd, 512,
                          (b2 / 4) * 128, (b2 % 4) * 128);
        }
    }
    grid_bar(bar, 6);

    // ---- P6: combine level 4 ----
    combine_level_256(wx_iou, wx_f, ioud, fd, c_out + (size_t)341 * HID,
                      h_out, c_out, h_bf, hs_bf, 85, 64, 1);
    grid_bar(bar, 7);

    // ---- levels 3..1: direct-load GEMM + combine ----
    small_gemm_phase(hs_bf, h_bf + (size_t)85 * HID, Uib, Ufb, ioud, fd, 64);
    grid_bar(bar, 8);
    combine_level_256(wx_iou, wx_f, ioud, fd, c_out + (size_t)85 * HID,
                      h_out, c_out, h_bf, hs_bf, 21, 16, 1);
    grid_bar(bar, 9);
    small_gemm_phase(hs_bf, h_bf + (size_t)21 * HID, Uib, Ufb, ioud, fd, 16);
    grid_bar(bar, 10);
    combine_level_256(wx_iou, wx_f, ioud, fd, c_out + (size_t)21 * HID,
                      h_out, c_out, h_bf, hs_bf, 5, 4, 1);
    grid_bar(bar, 11);
    small_gemm_phase(hs_bf, h_bf + (size_t)5 * HID, Uib, Ufb, ioud, fd, 4);
    grid_bar(bar, 12);
    combine_level_256(wx_iou, wx_f, ioud, fd, c_out + (size_t)5 * HID,
                      h_out, c_out, h_bf, hs_bf, 1, 1, 1);
    grid_bar(bar, 13);

    // ---- P13: root U-GEMMs (nl = 1) ----
    small_gemm_phase(hs_bf, h_bf + (size_t)1 * HID, Uib, Ufb, ioud, fd, 1);
    grid_bar(bar, 14);

    // ---- P14: root combine (block 0) || leaf h/c zeroing (all blocks, no consumer) ----
    if (blockIdx.x == 0) {
        const int j = threadIdx.x * 2;
        #pragma unroll
        for (int c = 0; c < 2; ++c) {
            const int jj = j + c;
            float iv = wx_iou[jj]        + ioud[jj];
            float ov = wx_iou[512 + jj]  + ioud[512 + jj];
            float uv = wx_iou[1024 + jj] + ioud[1024 + jj];
            float wf = wx_f[jj];
            float fc = 0.f;
            #pragma unroll
            for (int q = 0; q < 4; ++q)
                fc += (wf + fd[(size_t)q * 512 + jj]) * c_out[(size_t)(q + 1) * 512 + jj];
            float ig = 1.f / (1.f + expf(-iv));
            float og = 1.f / (1.f + expf(-ov));
            float ug = tanhf(uv);
            float cv2 = ig * ug + fc;
            c_out[jj] = cv2;
            h_out[jj] = og * tanhf(cv2);
        }
    }
    {
        float4* hleaf = (float4*)(h_out + (size_t)N_INT * HID);
        float4* cleaf = (float4*)(c_out + (size_t)N_INT * HID);
        const size_t Z = (size_t)(N_NODES - N_INT) * HID / 4;
        const float4 zz = {0.f, 0.f, 0.f, 0.f};
        for (size_t i = tid0; i < 2 * Z; i += gstr) {
            if (i < Z) hleaf[i] = zz;
            else       cleaf[i - Z] = zz;
        }
    }
}

// ======================================================================================
// Fallback multi-dispatch path (verified 275 us version), if cooperative launch fails.
// ======================================================================================
__global__ void prep_kernel(const float* __restrict__ x,
                            const float* __restrict__ W_iou,
                            const float* __restrict__ W_f,
                            const float* __restrict__ U_iou,
                            const float* __restrict__ U_f,
                            float* __restrict__ h_leaf,
                            float* __restrict__ c_leaf,
                            unsigned short* __restrict__ dstb)
{
    prep_body(x, W_iou, W_f, U_iou, U_f, h_leaf, c_leaf, dstb);
}

__global__ __launch_bounds__(256) void wgemm_kernel(
    const unsigned short* __restrict__ xb,
    const unsigned short* __restrict__ Wib,
    const unsigned short* __restrict__ Wfb,
    const float* __restrict__ b_iou, const float* __restrict__ b_f,
    float* __restrict__ wx_iou, float* __restrict__ wx_f)
{
    int b = blockIdx.x;
    if (b < 516) {
        gemm_tile_128(xb, N_INT, Wib, b_iou, wx_iou, 1536, (b / 12) * 128, (b % 12) * 128);
    } else {
        int b2 = b - 516;
        gemm_tile_128(xb, 1365, Wfb, b_f, wx_f, 512, (b2 / 4) * 128, (b2 % 4) * 128);
    }
}

__global__ __launch_bounds__(256) void gemm5_kernel(
    const unsigned short* __restrict__ hs_bf,
    const unsigned short* __restrict__ h6_bf,
    const unsigned short* __restrict__ Uib, const unsigned short* __restrict__ Ufb,
    float* __restrict__ ioud, float* __restrict__ fd)
{
    int b = blockIdx.x;
    if (b < 96) {
        gemm_tile_128(hs_bf, 1024, Uib, nullptr, ioud, 1536, (b / 12) * 128, (b % 12) * 128);
    } else {
        int b2 = b - 96;
        gemm_tile_128(h6_bf, 4096, Ufb, nullptr, fd, 512, (b2 / 4) * 128, (b2 % 4) * 128);
    }
}

__global__ __launch_bounds__(256) void gemm4_kernel(
    const unsigned short* __restrict__ hs_bf,
    const unsigned short* __restrict__ h5_bf,
    const unsigned short* __restrict__ Uib, const unsigned short* __restrict__ Ufb,
    float* __restrict__ ioud, float* __restrict__ fd)
{
    int b = blockIdx.x;
    if (b < 24) {
        gemm_tile_128(hs_bf, 256, Uib, nullptr, ioud, 1536, (b / 12) * 128, (b % 12) * 128);
    } else {
        int b2 = b - 24;
        gemm_tile_128(h5_bf, 1024, Ufb, nullptr, fd, 512, (b2 / 4) * 128, (b2 % 4) * 128);
    }
}

__global__ __launch_bounds__(256) void gemm_small_kernel(
    const unsigned short* __restrict__ hs_bf,
    const unsigned short* __restrict__ hch_bf,
    const unsigned short* __restrict__ Uib, const unsigned short* __restrict__ Ufb,
    float* __restrict__ ioud, float* __restrict__ fd, int nl)
{
    const int w = blockIdx.x * 4 + (threadIdx.x >> 6);
    const int mI = (nl + 15) >> 4;
    const int mF = (4 * nl + 15) >> 4;
    if (w < mI * 24) {
        direct_tile_16x64(hs_bf, nl, Uib, ioud, 1536, (w / 24) * 16, (w % 24) * 64);
    } else {
        int w2 = w - mI * 24;
        if (w2 < mF * 8)
            direct_tile_16x64(hch_bf, 4 * nl, Ufb, fd, 512, (w2 / 8) * 16, (w2 % 8) * 64);
    }
}

__global__ __launch_bounds__(256) void combine_kernel_fb(
    const float* __restrict__ wx_iou, const float* __restrict__ wx_f,
    const float* __restrict__ ioud, const float* __restrict__ fd,
    const float* __restrict__ c_child,
    float* __restrict__ h_out, float* __restrict__ c_out,
    unsigned short* __restrict__ h_bf, unsigned short* __restrict__ hs_bf,
    int s, int np, int hasU)
{
    combine_level_256(wx_iou, wx_f, ioud, fd, c_child, h_out, c_out, h_bf, hs_bf, s, np, hasU);
}

__global__ __launch_bounds__(128) void combine_root_kernel(
    const float* __restrict__ wx_iou, const float* __restrict__ wx_f,
    const float* __restrict__ ioud, const float* __restrict__ fd,
    const float* __restrict__ c_child,
    float* __restrict__ h_out, float* __restrict__ c_out)
{
    const int j4 = threadIdx.x << 2;
    #pragma unroll
    for (int c = 0; c < 4; ++c) {
        const int jj = j4 + c;
        float iv = wx_iou[jj]        + ioud[jj];
        float ov = wx_iou[512 + jj]  + ioud[512 + jj];
        float uv = wx_iou[1024 + jj] + ioud[1024 + jj];
        float wf = wx_f[jj];
        float fc = 0.f;
        #pragma unroll
        for (int q = 0; q < 4; ++q)
            fc += (wf + fd[(size_t)q * 512 + jj]) * c_child[(size_t)q * 512 + jj];
        float ig = 1.f / (1.f + expf(-iv));
        float og = 1.f / (1.f + expf(-ov));
        float ug = tanhf(uv);
        float cv2 = ig * ug + fc;
        c_out[jj] = cv2;
        h_out[jj] = og * tanhf(cv2);
    }
}

extern "C" void kernel_launch(void* const* d_in, const int* in_sizes, int n_in,
                              void* d_out, int out_size, void* d_ws, size_t ws_size,
                              hipStream_t stream) {
    const float* x     = (const float*)d_in[0];
    // d_in[1] = children: deterministic (4n+1..4n+4), not needed
    const float* W_iou = (const float*)d_in[2];
    const float* b_iou = (const float*)d_in[3];
    const float* W_f   = (const float*)d_in[4];
    const float* b_f   = (const float*)d_in[5];
    const float* U_iou = (const float*)d_in[6];
    const float* U_f   = (const float*)d_in[7];

    float* h_out = (float*)d_out;                       // N_NODES x 512
    float* c_out = h_out + (size_t)N_NODES * HID;       // N_NODES x 512

    // ---- workspace layout (fp32 region, then contiguous bf16 cast region) ----
    float* ws     = (float*)d_ws;
    float* wx_iou = ws;                                  // 5461*1536 f32
    float* wx_f   = wx_iou + (size_t)N_INT * 1536;       // 1365*512  f32
    float* ioud   = wx_f   + (size_t)1365 * 512;         // 1024*1536 f32
    float* fd     = ioud   + (size_t)1024 * 1536;        // 4096*512  f32
    unsigned short* xb   = (unsigned short*)(fd + (size_t)4096 * 512);
    unsigned short* Wib  = xb  + (size_t)N_INT * 512;    // 1536*512 bf16
    unsigned short* Wfb  = Wib + (size_t)1536 * 512;     // 512*512
    unsigned short* Uib  = Wfb + (size_t)512 * 512;      // 1536*512
    unsigned short* Ufb  = Uib + (size_t)1536 * 512;     // 512*512
    unsigned short* h_bf = Ufb + (size_t)512 * 512;      // 5461*512
    unsigned short* hs_bf= h_bf + (size_t)N_INT * 512;   // 1024*512
    unsigned* bar = (unsigned*)(hs_bf + (size_t)1024 * 512);  // barrier counter (64 B)

    // ---- cooperative mega-kernel path ----
    static int coopGrid = -1;   // -1 unknown, 0 disabled, >0 grid size
    if (coopGrid == -1) {
        int nb = 0;
        hipError_t qe = hipOccupancyMaxActiveBlocksPerMultiprocessor(&nb, mega_kernel, 256, 0);
        if (qe == hipSuccess && nb >= 1) {
            if (nb > 3) nb = 3;              // bound barrier arrival cost at 768 blocks
            coopGrid = nb * 256;
        } else {
            coopGrid = 0;
            (void)hipGetLastError();
        }
    }

    bool launched = false;
    if (coopGrid > 0) {
        hipError_t em = hipMemsetAsync(bar, 0, 64, stream);   // ws is re-poisoned each iter
        if (em == hipSuccess) {
            void* args[] = { (void*)&x, (void*)&W_iou, (void*)&b_iou, (void*)&W_f, (void*)&b_f,
                             (void*)&U_iou, (void*)&U_f, (void*)&h_out, (void*)&c_out,
                             (void*)&wx_iou, (void*)&wx_f, (void*)&ioud, (void*)&fd,
                             (void*)&xb, (void*)&Wib, (void*)&Wfb, (void*)&Uib, (void*)&Ufb,
                             (void*)&h_bf, (void*)&hs_bf, (void*)&bar };
            hipError_t e = hipLaunchCooperativeKernel((const void*)mega_kernel,
                                                      dim3(coopGrid), dim3(256), args, 0, stream);
            if (e == hipSuccess) {
                launched = true;
            } else {
                coopGrid = 0;
                (void)hipGetLastError();
            }
        } else {
            coopGrid = 0;
            (void)hipGetLastError();
        }
    }

    if (!launched) {
        // ---- previous verified 17-dispatch path ----
        prep_kernel<<<2048, 256, 0, stream>>>(x, W_iou, W_f, U_iou, U_f,
                                              h_out + (size_t)N_INT * HID,
                                              c_out + (size_t)N_INT * HID, xb);
        wgemm_kernel<<<516 + 44, 256, 0, stream>>>(xb, Wib, Wfb, b_iou, b_f, wx_iou, wx_f);
        combine_kernel_fb<<<1024, 256, 0, stream>>>(
            wx_iou, nullptr, nullptr, nullptr, nullptr,
            h_out, c_out, h_bf, hs_bf, 1365, 1024, 0);
        gemm5_kernel<<<224, 256, 0, stream>>>(hs_bf, h_bf + (size_t)1365 * HID, Uib, Ufb, ioud, fd);
        combine_kernel_fb<<<256, 256, 0, stream>>>(
            wx_iou, wx_f, ioud, fd, c_out + (size_t)1365 * HID,
            h_out, c_out, h_bf, hs_bf, 341, 256, 1);
        gemm4_kernel<<<56, 256, 0, stream>>>(hs_bf, h_bf + (size_t)341 * HID, Uib, Ufb, ioud, fd);
        combine_kernel_fb<<<64, 256, 0, stream>>>(
            wx_iou, wx_f, ioud, fd, c_out + (size_t)341 * HID,
            h_out, c_out, h_bf, hs_bf, 85, 64, 1);
        const int offs[9] = {0, 1, 5, 21, 85, 341, 1365, 5461, 21845};
        for (int l = 3; l >= 1; --l) {
            const int s  = offs[l];
            const int nl = offs[l + 1] - s;
            const int cb = offs[l + 1];
            const int mI = (nl + 15) >> 4;
            const int mF = (4 * nl + 15) >> 4;
            const int waves = mI * 24 + mF * 8;
            gemm_small_kernel<<<(waves + 3) / 4, 256, 0, stream>>>(
                hs_bf, h_bf + (size_t)cb * HID, Uib, Ufb, ioud, fd, nl);
            combine_kernel_fb<<<(nl + 3) / 4, 256, 0, stream>>>(
                wx_iou, wx_f, ioud, fd, c_out + (size_t)cb * HID,
                h_out, c_out, h_bf, hs_bf, s, nl >> 2, 1);
        }
        gemm_small_kernel<<<8, 256, 0, stream>>>(
            hs_bf, h_bf + (size_t)1 * HID, Uib, Ufb, ioud, fd, 1);
        combine_root_kernel<<<1, 128, 0, stream>>>(
            wx_iou, wx_f, ioud, fd, c_out + (size_t)1 * HID, h_out, c_out);
    }
}

// Round 3
// 431.349 us; speedup vs baseline: 1.6330x; 1.1587x over previous
//
#include <hip/hip_runtime.h>
#include <cmath>

// Tree constants (complete 4-ary tree, depth 7)
constexpr int N_NODES = 21845;
constexpr int N_INT   = 5461;   // internal nodes (levels 0..6)
constexpr int HID     = 512;

typedef short  short8  __attribute__((ext_vector_type(8)));
typedef float  floatx4 __attribute__((ext_vector_type(4)));

// fp32 -> bf16 bit pattern, round-to-nearest-even
__device__ __forceinline__ unsigned short f2bf(float f) {
    unsigned int u = __float_as_uint(f);
    u += 0x7fffu + ((u >> 16) & 1u);
    return (unsigned short)(u >> 16);
}

#define GLD_LDS(g, l) __builtin_amdgcn_global_load_lds( \
    (const __attribute__((address_space(1))) void*)(g), \
    (__attribute__((address_space(3))) void*)(l), 16, 0, 0)

// ================= hierarchical grid barrier =================
// Round-2 flat barrier measured ~30 us/barrier: 768 agent-scope RMWs on ONE cacheline
// serialize at the coherence point (~40 ns each). Fix: 32 group counters on separate
// 128 B lines (parallel arrival), group-lasts funnel into one global counter (<=32
// serial RMWs), final arriver release-stores a phase flag everyone polls.
// Release transitivity: observing an increment implies the incrementer's prior writes
// reached the coherence point (release RMW). Acquire fence on exit invalidates L1/L2.
// Layout (unsigned, stride 32 = 128 B lines):
//   [g*32] g=0..31 : group counters       [1024] : global counter
//   [1056]         : grid phase flag      [1088] : tail counter
//   [1120]         : tail phase flag
__device__ __forceinline__ void grid_bar(unsigned* bars, unsigned phase) {
    __syncthreads();
    if (threadIdx.x == 0) {
        const unsigned gsz = gridDim.x >> 5;          // blocks per group (NB multiple of 32)
        unsigned* gcnt = bars + (blockIdx.x & 31) * 32;
        unsigned* gl   = bars + 1024;
        unsigned* flag = bars + 1056;
        unsigned r = __hip_atomic_fetch_add(gcnt, 1u, __ATOMIC_RELEASE, __HIP_MEMORY_SCOPE_AGENT);
        if (r == phase * gsz - 1u) {                  // last of my group this phase
            unsigned rg = __hip_atomic_fetch_add(gl, 1u, __ATOMIC_RELEASE, __HIP_MEMORY_SCOPE_AGENT);
            if (rg == phase * 32u - 1u)               // last group overall
                __hip_atomic_store(flag, phase, __ATOMIC_RELEASE, __HIP_MEMORY_SCOPE_AGENT);
        }
        while (__hip_atomic_load(flag, __ATOMIC_RELAXED, __HIP_MEMORY_SCOPE_AGENT) < phase)
            __builtin_amdgcn_s_sleep(2);
        __builtin_amdgcn_fence(__ATOMIC_ACQUIRE, "agent");
    }
    __syncthreads();
}

// 16-block sub-barrier for the tiny tail levels (blocks 0..15 only)
__device__ __forceinline__ void tail_bar(unsigned* bars, unsigned phase) {
    __syncthreads();
    if (threadIdx.x == 0) {
        unsigned* cnt  = bars + 1088;
        unsigned* flag = bars + 1120;
        unsigned r = __hip_atomic_fetch_add(cnt, 1u, __ATOMIC_RELEASE, __HIP_MEMORY_SCOPE_AGENT);
        if (r == phase * 16u - 1u)
            __hip_atomic_store(flag, phase, __ATOMIC_RELEASE, __HIP_MEMORY_SCOPE_AGENT);
        while (__hip_atomic_load(flag, __ATOMIC_RELAXED, __HIP_MEMORY_SCOPE_AGENT) < phase)
            __builtin_amdgcn_s_sleep(1);
        __builtin_amdgcn_fence(__ATOMIC_ACQUIRE, "agent");
    }
    __syncthreads();
}

// ================= prep body (fallback path only) =================
__device__ __forceinline__ void prep_body(const float* __restrict__ x,
                                          const float* __restrict__ W_iou,
                                          const float* __restrict__ W_f,
                                          const float* __restrict__ U_iou,
                                          const float* __restrict__ U_f,
                                          float* __restrict__ h_leaf,
                                          float* __restrict__ c_leaf,
                                          unsigned short* __restrict__ dstb)
{
    const size_t Z  = (size_t)(N_NODES - N_INT) * HID / 4;
    const size_t C0 = (size_t)N_INT * 512 / 4;
    const size_t C1 = C0 + 1536 * 512 / 4;
    const size_t C2 = C1 + 512 * 512 / 4;
    const size_t C3 = C2 + 1536 * 512 / 4;
    const size_t C4 = C3 + 512 * 512 / 4;
    const size_t total = 2 * Z + C4;
    size_t i = (size_t)blockIdx.x * blockDim.x + threadIdx.x;
    const size_t stride = (size_t)gridDim.x * blockDim.x;
    const float4 zz = {0.f, 0.f, 0.f, 0.f};
    for (; i < total; i += stride) {
        if (i < 2 * Z) {
            if (i < Z) ((float4*)h_leaf)[i] = zz;
            else       ((float4*)c_leaf)[i - Z] = zz;
        } else {
            size_t k = i - 2 * Z;
            const float* src; size_t off;
            if (k < C0)      { src = x;     off = k; }
            else if (k < C1) { src = W_iou; off = k - C0; }
            else if (k < C2) { src = W_f;   off = k - C1; }
            else if (k < C3) { src = U_iou; off = k - C2; }
            else             { src = U_f;   off = k - C3; }
            float4 v = ((const float4*)src)[off];
            ushort4 o;
            o.x = f2bf(v.x); o.y = f2bf(v.y); o.z = f2bf(v.z); o.w = f2bf(v.w);
            ((ushort4*)dstb)[k] = o;
        }
    }
}

// ================= 128x128 bf16 MFMA GEMM tile (K=512), m97-style =================
__device__ __forceinline__ void gemm_tile_128(
    const unsigned short* __restrict__ A, int Arows,
    const unsigned short* __restrict__ B,
    const float* __restrict__ bias,
    float* __restrict__ C, int ldc,
    int bm, int bn)
{
    __shared__ short8 AsV[1024];   // 128 rows x 8 chunks (16B) = 16 KB
    __shared__ short8 BsV[1024];

    const int tid  = threadIdx.x;
    const int wave = tid >> 6;
    const int lane = tid & 63;
    const int quad = lane >> 4;
    const int lr   = lane & 15;
    const int wr = (wave >> 1) * 64;
    const int wc = (wave & 1) * 64;

    floatx4 acc[4][4];
    #pragma unroll
    for (int i = 0; i < 4; ++i)
        #pragma unroll
        for (int j = 0; j < 4; ++j)
            acc[i][j] = (floatx4){0.f, 0.f, 0.f, 0.f};

    int s_row[4], s_gk[4];
    #pragma unroll
    for (int it = 0; it < 4; ++it) {
        int c = it * 256 + wave * 64 + lane;
        s_row[it] = c >> 3;
        s_gk[it]  = (c & 7) ^ (s_row[it] & 7);
    }

    for (int k0 = 0; k0 < 512; k0 += 64) {
        #pragma unroll
        for (int it = 0; it < 4; ++it) {
            int row = s_row[it];
            int gm = bm + row; if (gm >= Arows) gm = Arows - 1;
            GLD_LDS(A + (size_t)gm * 512 + k0 + s_gk[it] * 8, &AsV[it * 256 + wave * 64]);
            int gn = bn + row;
            GLD_LDS(B + (size_t)gn * 512 + k0 + s_gk[it] * 8, &BsV[it * 256 + wave * 64]);
        }
        __syncthreads();

        #pragma unroll
        for (int kc = 0; kc < 2; ++kc) {
            short8 af[4], bfr[4];
            const int q = kc * 4 + quad;
            #pragma unroll
            for (int mt = 0; mt < 4; ++mt) {
                int row = wr + mt * 16 + lr;
                af[mt] = AsV[row * 8 + (q ^ (row & 7))];
            }
            #pragma unroll
            for (int nt = 0; nt < 4; ++nt) {
                int row = wc + nt * 16 + lr;
                bfr[nt] = BsV[row * 8 + (q ^ (row & 7))];
            }
            #pragma unroll
            for (int mt = 0; mt < 4; ++mt)
                #pragma unroll
                for (int nt = 0; nt < 4; ++nt)
                    acc[mt][nt] = __builtin_amdgcn_mfma_f32_16x16x32_bf16(
                        af[mt], bfr[nt], acc[mt][nt], 0, 0, 0);
        }
        __syncthreads();
    }

    #pragma unroll
    for (int mt = 0; mt < 4; ++mt) {
        #pragma unroll
        for (int r = 0; r < 4; ++r) {
            int gm = bm + wr + mt * 16 + quad * 4 + r;
            if (gm >= Arows) continue;
            #pragma unroll
            for (int nt = 0; nt < 4; ++nt) {
                int gn = bn + wc + nt * 16 + lr;
                float v = acc[mt][nt][r];
                if (bias) v += bias[gn];
                C[(size_t)gm * ldc + gn] = v;
            }
        }
    }
}

// ================= direct-from-global MFMA GEMM for tiny levels (no LDS, no barriers) ====
__device__ __forceinline__ void direct_tile_16x64(
    const unsigned short* __restrict__ A, int Arows,
    const unsigned short* __restrict__ B,
    float* __restrict__ C, int ldc,
    int m0, int n0)
{
    const int lane = threadIdx.x & 63;
    const int quad = lane >> 4;
    const int lr   = lane & 15;
    int am = m0 + lr; if (am >= Arows) am = Arows - 1;   // clamp (store-masked)
    const unsigned short* ap = A + (size_t)am * 512 + quad * 8;
    const unsigned short* bp = B + (size_t)(n0 + lr) * 512 + quad * 8;

    floatx4 acc[4];
    #pragma unroll
    for (int j = 0; j < 4; ++j) acc[j] = (floatx4){0.f, 0.f, 0.f, 0.f};

    #pragma unroll
    for (int k0 = 0; k0 < 512; k0 += 32) {
        short8 af = *(const short8*)(ap + k0);
        #pragma unroll
        for (int j = 0; j < 4; ++j) {
            short8 bf = *(const short8*)(bp + (size_t)j * 16 * 512 + k0);
            acc[j] = __builtin_amdgcn_mfma_f32_16x16x32_bf16(af, bf, acc[j], 0, 0, 0);
        }
    }

    #pragma unroll
    for (int j = 0; j < 4; ++j) {
        #pragma unroll
        for (int r = 0; r < 4; ++r) {
            int gm = m0 + quad * 4 + r;
            if (gm < Arows) C[(size_t)gm * ldc + n0 + j * 16 + lr] = acc[j][r];
        }
    }
}

// ================= small-level U-GEMMs (grid-stride over 16x64 wave tiles, nbsub blocks) ==
__device__ __forceinline__ void small_gemm_phase(
    const unsigned short* __restrict__ hs_bf,
    const unsigned short* __restrict__ hch_bf,
    const unsigned short* __restrict__ Uib, const unsigned short* __restrict__ Ufb,
    float* __restrict__ ioud, float* __restrict__ fd, int nl, int nbsub)
{
    const int mI = (nl + 15) >> 4;
    const int mF = (4 * nl + 15) >> 4;
    const int totW = mI * 24 + mF * 8;
    for (int w = blockIdx.x * 4 + (threadIdx.x >> 6); w < totW; w += nbsub * 4) {
        if (w < mI * 24)
            direct_tile_16x64(hs_bf, nl, Uib, ioud, 1536, (w / 24) * 16, (w % 24) * 64);
        else {
            int w2 = w - mI * 24;
            direct_tile_16x64(hch_bf, 4 * nl, Ufb, fd, 512, (w2 / 8) * 16, (w2 % 8) * 64);
        }
    }
}

// ================= 256-thread combine: 4 siblings/parent group, 8 hid elems/thread ========
__device__ void combine_level_256(
    const float* __restrict__ wx_iou, const float* __restrict__ wx_f,
    const float* __restrict__ ioud, const float* __restrict__ fd,
    const float* __restrict__ c_child,
    float* __restrict__ h_out, float* __restrict__ c_out,
    unsigned short* __restrict__ h_bf, unsigned short* __restrict__ hs_bf,
    int s, int np, int hasU, int nbsub)
{
    __shared__ floatx4 hsbuf[512];   // 8 KB
    const int k  = threadIdx.x >> 6;
    const int jg = threadIdx.x & 63;
    const int j8 = jg << 3;

    for (int tp = blockIdx.x; tp < np; tp += nbsub) {
        const int t = 4 * tp + k;
        const int n = s + t;
        const float* wrow = wx_iou + (size_t)n * 1536 + j8;
        floatx4 iv0 = *(const floatx4*)(wrow);
        floatx4 iv1 = *(const floatx4*)(wrow + 4);
        floatx4 ov0 = *(const floatx4*)(wrow + 512);
        floatx4 ov1 = *(const floatx4*)(wrow + 516);
        floatx4 uv0 = *(const floatx4*)(wrow + 1024);
        floatx4 uv1 = *(const floatx4*)(wrow + 1028);
        floatx4 fc0 = (floatx4){0.f,0.f,0.f,0.f};
        floatx4 fc1 = (floatx4){0.f,0.f,0.f,0.f};
        if (hasU) {
            const float* drow = ioud + (size_t)t * 1536 + j8;
            iv0 += *(const floatx4*)(drow);        iv1 += *(const floatx4*)(drow + 4);
            ov0 += *(const floatx4*)(drow + 512);  ov1 += *(const floatx4*)(drow + 516);
            uv0 += *(const floatx4*)(drow + 1024); uv1 += *(const floatx4*)(drow + 1028);
            const float* wfp = wx_f + (size_t)n * 512 + j8;
            floatx4 wf0 = *(const floatx4*)(wfp);
            floatx4 wf1 = *(const floatx4*)(wfp + 4);
            #pragma unroll
            for (int q = 0; q < 4; ++q) {
                const float* fp = fd + (size_t)(4 * t + q) * 512 + j8;
                const float* cp = c_child + (size_t)(4 * t + q) * 512 + j8;
                floatx4 f0 = *(const floatx4*)(fp),  f1 = *(const floatx4*)(fp + 4);
                floatx4 cv0 = *(const floatx4*)(cp), cv1 = *(const floatx4*)(cp + 4);
                fc0 += (wf0 + f0) * cv0;
                fc1 += (wf1 + f1) * cv1;
            }
        }
        floatx4 cn0, cn1, hn0, hn1;
        #pragma unroll
        for (int c = 0; c < 4; ++c) {
            float ig = 1.f / (1.f + expf(-iv0[c]));
            float og = 1.f / (1.f + expf(-ov0[c]));
            float ug = tanhf(uv0[c]);
            float cv2 = ig * ug + fc0[c];
            cn0[c] = cv2;
            hn0[c] = og * tanhf(cv2);
        }
        #pragma unroll
        for (int c = 0; c < 4; ++c) {
            float ig = 1.f / (1.f + expf(-iv1[c]));
            float og = 1.f / (1.f + expf(-ov1[c]));
            float ug = tanhf(uv1[c]);
            float cv2 = ig * ug + fc1[c];
            cn1[c] = cv2;
            hn1[c] = og * tanhf(cv2);
        }
        float* cop = c_out + (size_t)n * 512 + j8;
        float* hop = h_out + (size_t)n * 512 + j8;
        *(floatx4*)(cop)     = cn0;  *(floatx4*)(cop + 4) = cn1;
        *(floatx4*)(hop)     = hn0;  *(floatx4*)(hop + 4) = hn1;
        ushort4 hb0, hb1;
        hb0.x = f2bf(hn0[0]); hb0.y = f2bf(hn0[1]); hb0.z = f2bf(hn0[2]); hb0.w = f2bf(hn0[3]);
        hb1.x = f2bf(hn1[0]); hb1.y = f2bf(hn1[1]); hb1.z = f2bf(hn1[2]); hb1.w = f2bf(hn1[3]);
        *(ushort4*)(h_bf + (size_t)n * 512 + j8)     = hb0;
        *(ushort4*)(h_bf + (size_t)n * 512 + j8 + 4) = hb1;

        hsbuf[k * 128 + jg * 2]     = hn0;
        hsbuf[k * 128 + jg * 2 + 1] = hn1;
        __syncthreads();
        if (threadIdx.x < 64) {
            const int g = threadIdx.x;
            floatx4 s0 = hsbuf[g*2]   + hsbuf[128 + g*2]   + hsbuf[256 + g*2]   + hsbuf[384 + g*2];
            floatx4 s1 = hsbuf[g*2+1] + hsbuf[128 + g*2+1] + hsbuf[256 + g*2+1] + hsbuf[384 + g*2+1];
            ushort4 o0, o1;
            o0.x = f2bf(s0[0]); o0.y = f2bf(s0[1]); o0.z = f2bf(s0[2]); o0.w = f2bf(s0[3]);
            o1.x = f2bf(s1[0]); o1.y = f2bf(s1[1]); o1.z = f2bf(s1[2]); o1.w = f2bf(s1[3]);
            *(ushort4*)(hs_bf + (size_t)tp * 512 + g * 8)     = o0;
            *(ushort4*)(hs_bf + (size_t)tp * 512 + g * 8 + 4) = o1;
        }
        __syncthreads();
    }
}

// ======================================================================================
// MEGA KERNEL v3: 7 hierarchical full-grid barriers + 16-block tail for levels 3..0.
// vs round-2: flat 768-RMW barrier (~30 us) -> tree barrier (~3-4 us); the 7 tail
// barriers become 16-arrival sub-barriers (~0.5 us) overlapped with leaf zeroing.
// ======================================================================================
__global__ __launch_bounds__(256, 2) void mega_kernel(
    const float* __restrict__ x,
    const float* __restrict__ W_iou, const float* __restrict__ b_iou,
    const float* __restrict__ W_f,   const float* __restrict__ b_f,
    const float* __restrict__ U_iou, const float* __restrict__ U_f,
    float* __restrict__ h_out, float* __restrict__ c_out,
    float* __restrict__ wx_iou, float* __restrict__ wx_f,
    float* __restrict__ ioud, float* __restrict__ fd,
    unsigned short* __restrict__ xb,
    unsigned short* __restrict__ Wib, unsigned short* __restrict__ Wfb,
    unsigned short* __restrict__ Uib, unsigned short* __restrict__ Ufb,
    unsigned short* __restrict__ h_bf, unsigned short* __restrict__ hs_bf,
    unsigned* bar)
{
    const int NB = (int)gridDim.x;
    const size_t tid0 = (size_t)blockIdx.x * 256 + threadIdx.x;
    const size_t gstr = (size_t)NB * 256;

    // ---- P0: cast xb / Wib / Wfb (only operands P1 needs) ----
    {
        const size_t C0 = (size_t)N_INT * 512 / 4;
        const size_t C1 = C0 + 1536 * 512 / 4;
        const size_t C2 = C1 + 512 * 512 / 4;
        for (size_t k = tid0; k < C2; k += gstr) {
            const float* src; size_t off;
            if (k < C0)      { src = x;     off = k; }
            else if (k < C1) { src = W_iou; off = k - C0; }
            else             { src = W_f;   off = k - C1; }
            float4 v = ((const float4*)src)[off];
            ushort4 o;
            o.x = f2bf(v.x); o.y = f2bf(v.y); o.z = f2bf(v.z); o.w = f2bf(v.w);
            ((ushort4*)xb)[k] = o;
        }
    }
    grid_bar(bar, 1);

    // ---- P1: W-GEMMs (560 tile jobs); idle blocks (b>=560) cast U_iou/U_f ----
    for (int b = blockIdx.x; b < 560; b += NB) {
        if (b < 516)
            gemm_tile_128(xb, N_INT, Wib, b_iou, wx_iou, 1536, (b / 12) * 128, (b % 12) * 128);
        else {
            int b2 = b - 516;
            gemm_tile_128(xb, 1365, Wfb, b_f, wx_f, 512, (b2 / 4) * 128, (b2 % 4) * 128);
        }
    }
    {
        const size_t CU0 = 1536 * 512 / 4;
        const size_t CU1 = CU0 + 512 * 512 / 4;
        const int nIdle = NB - 560;
        if (nIdle > 0) {
            if (blockIdx.x >= 560) {
                size_t base = (size_t)(blockIdx.x - 560) * 256 + threadIdx.x;
                for (size_t k = base; k < CU1; k += (size_t)nIdle * 256) {
                    const float* src = (k < CU0) ? U_iou : U_f;
                    size_t off = (k < CU0) ? k : k - CU0;
                    float4 v = ((const float4*)src)[off];
                    ushort4 o;
                    o.x = f2bf(v.x); o.y = f2bf(v.y); o.z = f2bf(v.z); o.w = f2bf(v.w);
                    ((ushort4*)Uib)[k] = o;
                }
            }
        } else {
            for (size_t k = tid0; k < CU1; k += gstr) {
                const float* src = (k < CU0) ? U_iou : U_f;
                size_t off = (k < CU0) ? k : k - CU0;
                float4 v = ((const float4*)src)[off];
                ushort4 o;
                o.x = f2bf(v.x); o.y = f2bf(v.y); o.z = f2bf(v.z); o.w = f2bf(v.w);
                ((ushort4*)Uib)[k] = o;
            }
        }
    }
    grid_bar(bar, 2);

    // ---- P2: combine level 6 (children are leaves, no U terms) ----
    combine_level_256(wx_iou, nullptr, nullptr, nullptr, nullptr,
                      h_out, c_out, h_bf, hs_bf, 1365, 1024, 0, NB);
    grid_bar(bar, 3);

    // ---- P3: level-5 U-GEMMs (224 tile jobs) ----
    for (int b = blockIdx.x; b < 224; b += NB) {
        if (b < 96)
            gemm_tile_128(hs_bf, 1024, Uib, nullptr, ioud, 1536, (b / 12) * 128, (b % 12) * 128);
        else {
            int b2 = b - 96;
            gemm_tile_128(h_bf + (size_t)1365 * HID, 4096, Ufb, nullptr, fd, 512,
                          (b2 / 4) * 128, (b2 % 4) * 128);
        }
    }
    grid_bar(bar, 4);

    // ---- P4: combine level 5 ----
    combine_level_256(wx_iou, wx_f, ioud, fd, c_out + (size_t)1365 * HID,
                      h_out, c_out, h_bf, hs_bf, 341, 256, 1, NB);
    grid_bar(bar, 5);

    // ---- P5: level-4 U-GEMMs (56 tile jobs) ----
    for (int b = blockIdx.x; b < 56; b += NB) {
        if (b < 24)
            gemm_tile_128(hs_bf, 256, Uib, nullptr, ioud, 1536, (b / 12) * 128, (b % 12) * 128);
        else {
            int b2 = b - 24;
            gemm_tile_128(h_bf + (size_t)341 * HID, 1024, Ufb, nullptr, fd, 512,
                          (b2 / 4) * 128, (b2 % 4) * 128);
        }
    }
    grid_bar(bar, 6);

    // ---- P6: combine level 4 ----
    combine_level_256(wx_iou, wx_f, ioud, fd, c_out + (size_t)341 * HID,
                      h_out, c_out, h_bf, hs_bf, 85, 64, 1, NB);
    grid_bar(bar, 7);

    if (blockIdx.x < 16) {
        // ---- tail: levels 3..1 + root, 16 blocks, sub-barriers only ----
        small_gemm_phase(hs_bf, h_bf + (size_t)85 * HID, Uib, Ufb, ioud, fd, 64, 16);
        tail_bar(bar, 1);
        combine_level_256(wx_iou, wx_f, ioud, fd, c_out + (size_t)85 * HID,
                          h_out, c_out, h_bf, hs_bf, 21, 16, 1, 16);
        tail_bar(bar, 2);
        small_gemm_phase(hs_bf, h_bf + (size_t)21 * HID, Uib, Ufb, ioud, fd, 16, 16);
        tail_bar(bar, 3);
        combine_level_256(wx_iou, wx_f, ioud, fd, c_out + (size_t)21 * HID,
                          h_out, c_out, h_bf, hs_bf, 5, 4, 1, 16);
        tail_bar(bar, 4);
        small_gemm_phase(hs_bf, h_bf + (size_t)5 * HID, Uib, Ufb, ioud, fd, 4, 16);
        tail_bar(bar, 5);
        combine_level_256(wx_iou, wx_f, ioud, fd, c_out + (size_t)5 * HID,
                          h_out, c_out, h_bf, hs_bf, 1, 1, 1, 16);
        tail_bar(bar, 6);
        small_gemm_phase(hs_bf, h_bf + (size_t)1 * HID, Uib, Ufb, ioud, fd, 1, 16);
        tail_bar(bar, 7);
        // root combine (node 0): block 0, 256 threads x 2 elems
        if (blockIdx.x == 0) {
            const int j = threadIdx.x * 2;
            #pragma unroll
            for (int c = 0; c < 2; ++c) {
                const int jj = j + c;
                float iv = wx_iou[jj]        + ioud[jj];
                float ov = wx_iou[512 + jj]  + ioud[512 + jj];
                float uv = wx_iou[1024 + jj] + ioud[1024 + jj];
                float wf = wx_f[jj];
                float fc = 0.f;
                #pragma unroll
                for (int q = 0; q < 4; ++q)
                    fc += (wf + fd[(size_t)q * 512 + jj]) * c_out[(size_t)(q + 1) * 512 + jj];
                float ig = 1.f / (1.f + expf(-iv));
                float og = 1.f / (1.f + expf(-ov));
                float ug = tanhf(uv);
                float cv2 = ig * ug + fc;
                c_out[jj] = cv2;
                h_out[jj] = og * tanhf(cv2);
            }
        }
    } else {
        // ---- leaf h/c zeroing (no consumer), overlaps the tail ----
        float4* hleaf = (float4*)(h_out + (size_t)N_INT * HID);
        float4* cleaf = (float4*)(c_out + (size_t)N_INT * HID);
        const size_t Z = (size_t)(N_NODES - N_INT) * HID / 4;
        const float4 zz = {0.f, 0.f, 0.f, 0.f};
        size_t base = (size_t)(blockIdx.x - 16) * 256 + threadIdx.x;
        const size_t zstr = (size_t)(NB - 16) * 256;
        for (size_t i = base; i < 2 * Z; i += zstr) {
            if (i < Z) hleaf[i] = zz;
            else       cleaf[i - Z] = zz;
        }
    }
}

// ======================================================================================
// Fallback multi-dispatch path (verified 275 us version), if cooperative launch fails.
// ======================================================================================
__global__ void prep_kernel(const float* __restrict__ x,
                            const float* __restrict__ W_iou,
                            const float* __restrict__ W_f,
                            const float* __restrict__ U_iou,
                            const float* __restrict__ U_f,
                            float* __restrict__ h_leaf,
                            float* __restrict__ c_leaf,
                            unsigned short* __restrict__ dstb)
{
    prep_body(x, W_iou, W_f, U_iou, U_f, h_leaf, c_leaf, dstb);
}

__global__ __launch_bounds__(256) void wgemm_kernel(
    const unsigned short* __restrict__ xb,
    const unsigned short* __restrict__ Wib,
    const unsigned short* __restrict__ Wfb,
    const float* __restrict__ b_iou, const float* __restrict__ b_f,
    float* __restrict__ wx_iou, float* __restrict__ wx_f)
{
    int b = blockIdx.x;
    if (b < 516) {
        gemm_tile_128(xb, N_INT, Wib, b_iou, wx_iou, 1536, (b / 12) * 128, (b % 12) * 128);
    } else {
        int b2 = b - 516;
        gemm_tile_128(xb, 1365, Wfb, b_f, wx_f, 512, (b2 / 4) * 128, (b2 % 4) * 128);
    }
}

__global__ __launch_bounds__(256) void gemm5_kernel(
    const unsigned short* __restrict__ hs_bf,
    const unsigned short* __restrict__ h6_bf,
    const unsigned short* __restrict__ Uib, const unsigned short* __restrict__ Ufb,
    float* __restrict__ ioud, float* __restrict__ fd)
{
    int b = blockIdx.x;
    if (b < 96) {
        gemm_tile_128(hs_bf, 1024, Uib, nullptr, ioud, 1536, (b / 12) * 128, (b % 12) * 128);
    } else {
        int b2 = b - 96;
        gemm_tile_128(h6_bf, 4096, Ufb, nullptr, fd, 512, (b2 / 4) * 128, (b2 % 4) * 128);
    }
}

__global__ __launch_bounds__(256) void gemm4_kernel(
    const unsigned short* __restrict__ hs_bf,
    const unsigned short* __restrict__ h5_bf,
    const unsigned short* __restrict__ Uib, const unsigned short* __restrict__ Ufb,
    float* __restrict__ ioud, float* __restrict__ fd)
{
    int b = blockIdx.x;
    if (b < 24) {
        gemm_tile_128(hs_bf, 256, Uib, nullptr, ioud, 1536, (b / 12) * 128, (b % 12) * 128);
    } else {
        int b2 = b - 24;
        gemm_tile_128(h5_bf, 1024, Ufb, nullptr, fd, 512, (b2 / 4) * 128, (b2 % 4) * 128);
    }
}

__global__ __launch_bounds__(256) void gemm_small_kernel(
    const unsigned short* __restrict__ hs_bf,
    const unsigned short* __restrict__ hch_bf,
    const unsigned short* __restrict__ Uib, const unsigned short* __restrict__ Ufb,
    float* __restrict__ ioud, float* __restrict__ fd, int nl)
{
    const int w = blockIdx.x * 4 + (threadIdx.x >> 6);
    const int mI = (nl + 15) >> 4;
    const int mF = (4 * nl + 15) >> 4;
    if (w < mI * 24) {
        direct_tile_16x64(hs_bf, nl, Uib, ioud, 1536, (w / 24) * 16, (w % 24) * 64);
    } else {
        int w2 = w - mI * 24;
        if (w2 < mF * 8)
            direct_tile_16x64(hch_bf, 4 * nl, Ufb, fd, 512, (w2 / 8) * 16, (w2 % 8) * 64);
    }
}

__global__ __launch_bounds__(256) void combine_kernel_fb(
    const float* __restrict__ wx_iou, const float* __restrict__ wx_f,
    const float* __restrict__ ioud, const float* __restrict__ fd,
    const float* __restrict__ c_child,
    float* __restrict__ h_out, float* __restrict__ c_out,
    unsigned short* __restrict__ h_bf, unsigned short* __restrict__ hs_bf,
    int s, int np, int hasU)
{
    combine_level_256(wx_iou, wx_f, ioud, fd, c_child, h_out, c_out, h_bf, hs_bf,
                      s, np, hasU, (int)gridDim.x);
}

__global__ __launch_bounds__(128) void combine_root_kernel(
    const float* __restrict__ wx_iou, const float* __restrict__ wx_f,
    const float* __restrict__ ioud, const float* __restrict__ fd,
    const float* __restrict__ c_child,
    float* __restrict__ h_out, float* __restrict__ c_out)
{
    const int j4 = threadIdx.x << 2;
    #pragma unroll
    for (int c = 0; c < 4; ++c) {
        const int jj = j4 + c;
        float iv = wx_iou[jj]        + ioud[jj];
        float ov = wx_iou[512 + jj]  + ioud[512 + jj];
        float uv = wx_iou[1024 + jj] + ioud[1024 + jj];
        float wf = wx_f[jj];
        float fc = 0.f;
        #pragma unroll
        for (int q = 0; q < 4; ++q)
            fc += (wf + fd[(size_t)q * 512 + jj]) * c_child[(size_t)q * 512 + jj];
        float ig = 1.f / (1.f + expf(-iv));
        float og = 1.f / (1.f + expf(-ov));
        float ug = tanhf(uv);
        float cv2 = ig * ug + fc;
        c_out[jj] = cv2;
        h_out[jj] = og * tanhf(cv2);
    }
}

extern "C" void kernel_launch(void* const* d_in, const int* in_sizes, int n_in,
                              void* d_out, int out_size, void* d_ws, size_t ws_size,
                              hipStream_t stream) {
    const float* x     = (const float*)d_in[0];
    // d_in[1] = children: deterministic (4n+1..4n+4), not needed
    const float* W_iou = (const float*)d_in[2];
    const float* b_iou = (const float*)d_in[3];
    const float* W_f   = (const float*)d_in[4];
    const float* b_f   = (const float*)d_in[5];
    const float* U_iou = (const float*)d_in[6];
    const float* U_f   = (const float*)d_in[7];

    float* h_out = (float*)d_out;                       // N_NODES x 512
    float* c_out = h_out + (size_t)N_NODES * HID;       // N_NODES x 512

    // ---- workspace layout (fp32 region, then contiguous bf16 cast region) ----
    float* ws     = (float*)d_ws;
    float* wx_iou = ws;                                  // 5461*1536 f32
    float* wx_f   = wx_iou + (size_t)N_INT * 1536;       // 1365*512  f32
    float* ioud   = wx_f   + (size_t)1365 * 512;         // 1024*1536 f32
    float* fd     = ioud   + (size_t)1024 * 1536;        // 4096*512  f32
    unsigned short* xb   = (unsigned short*)(fd + (size_t)4096 * 512);
    unsigned short* Wib  = xb  + (size_t)N_INT * 512;    // 1536*512 bf16
    unsigned short* Wfb  = Wib + (size_t)1536 * 512;     // 512*512
    unsigned short* Uib  = Wfb + (size_t)512 * 512;      // 1536*512
    unsigned short* Ufb  = Uib + (size_t)1536 * 512;     // 512*512
    unsigned short* h_bf = Ufb + (size_t)512 * 512;      // 5461*512
    unsigned short* hs_bf= h_bf + (size_t)N_INT * 512;   // 1024*512
    unsigned* bar = (unsigned*)(hs_bf + (size_t)1024 * 512);  // barrier lines (4608 B)

    // ---- cooperative mega-kernel path ----
    static int coopGrid = -1;   // -1 unknown, 0 disabled, >0 grid size
    if (coopGrid == -1) {
        int nb = 0;
        hipError_t qe = hipOccupancyMaxActiveBlocksPerMultiprocessor(&nb, mega_kernel, 256, 0);
        if (qe == hipSuccess && nb >= 1) {
            if (nb > 4) nb = 4;
            coopGrid = nb * 256;             // multiple of 32 (barrier groups)
        } else {
            coopGrid = 0;
            (void)hipGetLastError();
        }
    }

    bool launched = false;
    if (coopGrid > 0) {
        hipError_t em = hipMemsetAsync(bar, 0, 4608, stream);   // ws re-poisoned each iter
        if (em == hipSuccess) {
            void* args[] = { (void*)&x, (void*)&W_iou, (void*)&b_iou, (void*)&W_f, (void*)&b_f,
                             (void*)&U_iou, (void*)&U_f, (void*)&h_out, (void*)&c_out,
                             (void*)&wx_iou, (void*)&wx_f, (void*)&ioud, (void*)&fd,
                             (void*)&xb, (void*)&Wib, (void*)&Wfb, (void*)&Uib, (void*)&Ufb,
                             (void*)&h_bf, (void*)&hs_bf, (void*)&bar };
            hipError_t e = hipLaunchCooperativeKernel((const void*)mega_kernel,
                                                      dim3(coopGrid), dim3(256), args, 0, stream);
            if (e == hipSuccess) {
                launched = true;
            } else {
                coopGrid = 0;
                (void)hipGetLastError();
            }
        } else {
            coopGrid = 0;
            (void)hipGetLastError();
        }
    }

    if (!launched) {
        // ---- previous verified 17-dispatch path ----
        prep_kernel<<<2048, 256, 0, stream>>>(x, W_iou, W_f, U_iou, U_f,
                                              h_out + (size_t)N_INT * HID,
                                              c_out + (size_t)N_INT * HID, xb);
        wgemm_kernel<<<516 + 44, 256, 0, stream>>>(xb, Wib, Wfb, b_iou, b_f, wx_iou, wx_f);
        combine_kernel_fb<<<1024, 256, 0, stream>>>(
            wx_iou, nullptr, nullptr, nullptr, nullptr,
            h_out, c_out, h_bf, hs_bf, 1365, 1024, 0);
        gemm5_kernel<<<224, 256, 0, stream>>>(hs_bf, h_bf + (size_t)1365 * HID, Uib, Ufb, ioud, fd);
        combine_kernel_fb<<<256, 256, 0, stream>>>(
            wx_iou, wx_f, ioud, fd, c_out + (size_t)1365 * HID,
            h_out, c_out, h_bf, hs_bf, 341, 256, 1);
        gemm4_kernel<<<56, 256, 0, stream>>>(hs_bf, h_bf + (size_t)341 * HID, Uib, Ufb, ioud, fd);
        combine_kernel_fb<<<64, 256, 0, stream>>>(
            wx_iou, wx_f, ioud, fd, c_out + (size_t)341 * HID,
            h_out, c_out, h_bf, hs_bf, 85, 64, 1);
        const int offs[9] = {0, 1, 5, 21, 85, 341, 1365, 5461, 21845};
        for (int l = 3; l >= 1; --l) {
            const int s  = offs[l];
            const int nl = offs[l + 1] - s;
            const int cb = offs[l + 1];
            const int mI = (nl + 15) >> 4;
            const int mF = (4 * nl + 15) >> 4;
            const int waves = mI * 24 + mF * 8;
            gemm_small_kernel<<<(waves + 3) / 4, 256, 0, stream>>>(
                hs_bf, h_bf + (size_t)cb * HID, Uib, Ufb, ioud, fd, nl);
            combine_kernel_fb<<<(nl + 3) / 4, 256, 0, stream>>>(
                wx_iou, wx_f, ioud, fd, c_out + (size_t)cb * HID,
                h_out, c_out, h_bf, hs_bf, s, nl >> 2, 1);
        }
        gemm_small_kernel<<<8, 256, 0, stream>>>(
            hs_bf, h_bf + (size_t)1 * HID, Uib, Ufb, ioud, fd, 1);
        combine_root_kernel<<<1, 128, 0, stream>>>(
            wx_iou, wx_f, ioud, fd, c_out + (size_t)1 * HID, h_out, c_out);
    }
}

// Round 4
// 430.203 us; speedup vs baseline: 1.6373x; 1.0027x over previous
//
#include <hip/hip_runtime.h>
#include <cmath>

// Tree constants (complete 4-ary tree, depth 7)
constexpr int N_NODES = 21845;
constexpr int N_INT   = 5461;   // internal nodes (levels 0..6)
constexpr int HID     = 512;

typedef short  short8  __attribute__((ext_vector_type(8)));
typedef float  floatx4 __attribute__((ext_vector_type(4)));

// fp32 -> bf16 bit pattern, round-to-nearest-even
__device__ __forceinline__ unsigned short f2bf(float f) {
    unsigned int u = __float_as_uint(f);
    u += 0x7fffu + ((u >> 16) & 1u);
    return (unsigned short)(u >> 16);
}

#define GLD_LDS(g, l) __builtin_amdgcn_global_load_lds( \
    (const __attribute__((address_space(1))) void*)(g), \
    (__attribute__((address_space(3))) void*)(l), 16, 0, 0)

// ================= fan-out grid barrier =================
// Rounds 2-3 measured ~40 us/barrier INDEPENDENT of arrival structure (flat 768-RMW vs
// 32-line tree). Shared trait: single-line DETECTION - ~1000 block-leaders spin-poll one
// cacheline at the coherence point; after the flag store, a full rotation of ~1000
// contended reads (~35ns each) = ~35us. Fix: final arriver broadcasts the phase to 32
// flag lines (one release fence + 32 relaxed stores); each block polls only its group's
// line (<=32 pollers/line, s_sleep backoff) -> detection ~1us.
// Correctness: member arrival RMW (ACQ_REL) -> group-last root RMW (ACQ_REL) -> final
// arriver release FENCE + relaxed flag stores; poller observes flag, acquire FENCE =>
// fence-fence synchronizes-with; transitive visibility of all blocks' phase writes.
// Layout (unsigned words, 128B-line stride 32):
//   [g*32]        g=0..31 : group arrival counters
//   [1024+g*32]   g=0..31 : group phase flags
//   [2048] root counter   [2080] tail counter   [2112] tail flag
__device__ __forceinline__ void grid_bar(unsigned* bars, unsigned phase) {
    __syncthreads();
    if (threadIdx.x == 0) {
        const unsigned g   = blockIdx.x & 31;
        const unsigned gsz = gridDim.x >> 5;          // NB is a multiple of 32
        unsigned* gcnt  = bars + g * 32;
        unsigned* gflag = bars + 1024 + g * 32;
        unsigned r = __hip_atomic_fetch_add(gcnt, 1u, __ATOMIC_ACQ_REL, __HIP_MEMORY_SCOPE_AGENT);
        if (r == phase * gsz - 1u) {                  // last of my group this phase
            unsigned rr = __hip_atomic_fetch_add(bars + 2048, 1u, __ATOMIC_ACQ_REL,
                                                 __HIP_MEMORY_SCOPE_AGENT);
            if (rr == phase * 32u - 1u) {             // last group overall: broadcast
                __builtin_amdgcn_fence(__ATOMIC_RELEASE, "agent");
                #pragma unroll
                for (int i = 0; i < 32; ++i)
                    __hip_atomic_store(bars + 1024 + i * 32, phase, __ATOMIC_RELAXED,
                                       __HIP_MEMORY_SCOPE_AGENT);
            }
        }
        while (__hip_atomic_load(gflag, __ATOMIC_RELAXED, __HIP_MEMORY_SCOPE_AGENT) < phase)
            __builtin_amdgcn_s_sleep(8);
        __builtin_amdgcn_fence(__ATOMIC_ACQUIRE, "agent");
    }
    __syncthreads();
}

// 16-block sub-barrier for the tiny tail levels (blocks 0..15 only; 16 pollers = cheap)
__device__ __forceinline__ void tail_bar(unsigned* bars, unsigned phase) {
    __syncthreads();
    if (threadIdx.x == 0) {
        unsigned* cnt  = bars + 2080;
        unsigned* flag = bars + 2112;
        unsigned r = __hip_atomic_fetch_add(cnt, 1u, __ATOMIC_ACQ_REL, __HIP_MEMORY_SCOPE_AGENT);
        if (r == phase * 16u - 1u)
            __hip_atomic_store(flag, phase, __ATOMIC_RELEASE, __HIP_MEMORY_SCOPE_AGENT);
        while (__hip_atomic_load(flag, __ATOMIC_RELAXED, __HIP_MEMORY_SCOPE_AGENT) < phase)
            __builtin_amdgcn_s_sleep(2);
        __builtin_amdgcn_fence(__ATOMIC_ACQUIRE, "agent");
    }
    __syncthreads();
}

// ================= prep body (fallback path only) =================
__device__ __forceinline__ void prep_body(const float* __restrict__ x,
                                          const float* __restrict__ W_iou,
                                          const float* __restrict__ W_f,
                                          const float* __restrict__ U_iou,
                                          const float* __restrict__ U_f,
                                          float* __restrict__ h_leaf,
                                          float* __restrict__ c_leaf,
                                          unsigned short* __restrict__ dstb)
{
    const size_t Z  = (size_t)(N_NODES - N_INT) * HID / 4;
    const size_t C0 = (size_t)N_INT * 512 / 4;
    const size_t C1 = C0 + 1536 * 512 / 4;
    const size_t C2 = C1 + 512 * 512 / 4;
    const size_t C3 = C2 + 1536 * 512 / 4;
    const size_t C4 = C3 + 512 * 512 / 4;
    const size_t total = 2 * Z + C4;
    size_t i = (size_t)blockIdx.x * blockDim.x + threadIdx.x;
    const size_t stride = (size_t)gridDim.x * blockDim.x;
    const float4 zz = {0.f, 0.f, 0.f, 0.f};
    for (; i < total; i += stride) {
        if (i < 2 * Z) {
            if (i < Z) ((float4*)h_leaf)[i] = zz;
            else       ((float4*)c_leaf)[i - Z] = zz;
        } else {
            size_t k = i - 2 * Z;
            const float* src; size_t off;
            if (k < C0)      { src = x;     off = k; }
            else if (k < C1) { src = W_iou; off = k - C0; }
            else if (k < C2) { src = W_f;   off = k - C1; }
            else if (k < C3) { src = U_iou; off = k - C2; }
            else             { src = U_f;   off = k - C3; }
            float4 v = ((const float4*)src)[off];
            ushort4 o;
            o.x = f2bf(v.x); o.y = f2bf(v.y); o.z = f2bf(v.z); o.w = f2bf(v.w);
            ((ushort4*)dstb)[k] = o;
        }
    }
}

// ================= 128x128 bf16 MFMA GEMM tile (K=512), m97-style =================
__device__ __forceinline__ void gemm_tile_128(
    const unsigned short* __restrict__ A, int Arows,
    const unsigned short* __restrict__ B,
    const float* __restrict__ bias,
    float* __restrict__ C, int ldc,
    int bm, int bn)
{
    __shared__ short8 AsV[1024];   // 128 rows x 8 chunks (16B) = 16 KB
    __shared__ short8 BsV[1024];

    const int tid  = threadIdx.x;
    const int wave = tid >> 6;
    const int lane = tid & 63;
    const int quad = lane >> 4;
    const int lr   = lane & 15;
    const int wr = (wave >> 1) * 64;
    const int wc = (wave & 1) * 64;

    floatx4 acc[4][4];
    #pragma unroll
    for (int i = 0; i < 4; ++i)
        #pragma unroll
        for (int j = 0; j < 4; ++j)
            acc[i][j] = (floatx4){0.f, 0.f, 0.f, 0.f};

    int s_row[4], s_gk[4];
    #pragma unroll
    for (int it = 0; it < 4; ++it) {
        int c = it * 256 + wave * 64 + lane;
        s_row[it] = c >> 3;
        s_gk[it]  = (c & 7) ^ (s_row[it] & 7);
    }

    for (int k0 = 0; k0 < 512; k0 += 64) {
        #pragma unroll
        for (int it = 0; it < 4; ++it) {
            int row = s_row[it];
            int gm = bm + row; if (gm >= Arows) gm = Arows - 1;
            GLD_LDS(A + (size_t)gm * 512 + k0 + s_gk[it] * 8, &AsV[it * 256 + wave * 64]);
            int gn = bn + row;
            GLD_LDS(B + (size_t)gn * 512 + k0 + s_gk[it] * 8, &BsV[it * 256 + wave * 64]);
        }
        __syncthreads();

        #pragma unroll
        for (int kc = 0; kc < 2; ++kc) {
            short8 af[4], bfr[4];
            const int q = kc * 4 + quad;
            #pragma unroll
            for (int mt = 0; mt < 4; ++mt) {
                int row = wr + mt * 16 + lr;
                af[mt] = AsV[row * 8 + (q ^ (row & 7))];
            }
            #pragma unroll
            for (int nt = 0; nt < 4; ++nt) {
                int row = wc + nt * 16 + lr;
                bfr[nt] = BsV[row * 8 + (q ^ (row & 7))];
            }
            #pragma unroll
            for (int mt = 0; mt < 4; ++mt)
                #pragma unroll
                for (int nt = 0; nt < 4; ++nt)
                    acc[mt][nt] = __builtin_amdgcn_mfma_f32_16x16x32_bf16(
                        af[mt], bfr[nt], acc[mt][nt], 0, 0, 0);
        }
        __syncthreads();
    }

    #pragma unroll
    for (int mt = 0; mt < 4; ++mt) {
        #pragma unroll
        for (int r = 0; r < 4; ++r) {
            int gm = bm + wr + mt * 16 + quad * 4 + r;
            if (gm >= Arows) continue;
            #pragma unroll
            for (int nt = 0; nt < 4; ++nt) {
                int gn = bn + wc + nt * 16 + lr;
                float v = acc[mt][nt][r];
                if (bias) v += bias[gn];
                C[(size_t)gm * ldc + gn] = v;
            }
        }
    }
}

// ================= direct-from-global MFMA GEMM for tiny levels (no LDS, no barriers) ====
__device__ __forceinline__ void direct_tile_16x64(
    const unsigned short* __restrict__ A, int Arows,
    const unsigned short* __restrict__ B,
    float* __restrict__ C, int ldc,
    int m0, int n0)
{
    const int lane = threadIdx.x & 63;
    const int quad = lane >> 4;
    const int lr   = lane & 15;
    int am = m0 + lr; if (am >= Arows) am = Arows - 1;   // clamp (store-masked)
    const unsigned short* ap = A + (size_t)am * 512 + quad * 8;
    const unsigned short* bp = B + (size_t)(n0 + lr) * 512 + quad * 8;

    floatx4 acc[4];
    #pragma unroll
    for (int j = 0; j < 4; ++j) acc[j] = (floatx4){0.f, 0.f, 0.f, 0.f};

    #pragma unroll
    for (int k0 = 0; k0 < 512; k0 += 32) {
        short8 af = *(const short8*)(ap + k0);
        #pragma unroll
        for (int j = 0; j < 4; ++j) {
            short8 bf = *(const short8*)(bp + (size_t)j * 16 * 512 + k0);
            acc[j] = __builtin_amdgcn_mfma_f32_16x16x32_bf16(af, bf, acc[j], 0, 0, 0);
        }
    }

    #pragma unroll
    for (int j = 0; j < 4; ++j) {
        #pragma unroll
        for (int r = 0; r < 4; ++r) {
            int gm = m0 + quad * 4 + r;
            if (gm < Arows) C[(size_t)gm * ldc + n0 + j * 16 + lr] = acc[j][r];
        }
    }
}

// ================= small-level U-GEMMs (grid-stride over 16x64 wave tiles, nbsub blocks) ==
__device__ __forceinline__ void small_gemm_phase(
    const unsigned short* __restrict__ hs_bf,
    const unsigned short* __restrict__ hch_bf,
    const unsigned short* __restrict__ Uib, const unsigned short* __restrict__ Ufb,
    float* __restrict__ ioud, float* __restrict__ fd, int nl, int nbsub)
{
    const int mI = (nl + 15) >> 4;
    const int mF = (4 * nl + 15) >> 4;
    const int totW = mI * 24 + mF * 8;
    for (int w = blockIdx.x * 4 + (threadIdx.x >> 6); w < totW; w += nbsub * 4) {
        if (w < mI * 24)
            direct_tile_16x64(hs_bf, nl, Uib, ioud, 1536, (w / 24) * 16, (w % 24) * 64);
        else {
            int w2 = w - mI * 24;
            direct_tile_16x64(hch_bf, 4 * nl, Ufb, fd, 512, (w2 / 8) * 16, (w2 % 8) * 64);
        }
    }
}

// ================= 256-thread combine: 4 siblings/parent group, 8 hid elems/thread ========
__device__ void combine_level_256(
    const float* __restrict__ wx_iou, const float* __restrict__ wx_f,
    const float* __restrict__ ioud, const float* __restrict__ fd,
    const float* __restrict__ c_child,
    float* __restrict__ h_out, float* __restrict__ c_out,
    unsigned short* __restrict__ h_bf, unsigned short* __restrict__ hs_bf,
    int s, int np, int hasU, int nbsub)
{
    __shared__ floatx4 hsbuf[512];   // 8 KB
    const int k  = threadIdx.x >> 6;
    const int jg = threadIdx.x & 63;
    const int j8 = jg << 3;

    for (int tp = blockIdx.x; tp < np; tp += nbsub) {
        const int t = 4 * tp + k;
        const int n = s + t;
        const float* wrow = wx_iou + (size_t)n * 1536 + j8;
        floatx4 iv0 = *(const floatx4*)(wrow);
        floatx4 iv1 = *(const floatx4*)(wrow + 4);
        floatx4 ov0 = *(const floatx4*)(wrow + 512);
        floatx4 ov1 = *(const floatx4*)(wrow + 516);
        floatx4 uv0 = *(const floatx4*)(wrow + 1024);
        floatx4 uv1 = *(const floatx4*)(wrow + 1028);
        floatx4 fc0 = (floatx4){0.f,0.f,0.f,0.f};
        floatx4 fc1 = (floatx4){0.f,0.f,0.f,0.f};
        if (hasU) {
            const float* drow = ioud + (size_t)t * 1536 + j8;
            iv0 += *(const floatx4*)(drow);        iv1 += *(const floatx4*)(drow + 4);
            ov0 += *(const floatx4*)(drow + 512);  ov1 += *(const floatx4*)(drow + 516);
            uv0 += *(const floatx4*)(drow + 1024); uv1 += *(const floatx4*)(drow + 1028);
            const float* wfp = wx_f + (size_t)n * 512 + j8;
            floatx4 wf0 = *(const floatx4*)(wfp);
            floatx4 wf1 = *(const floatx4*)(wfp + 4);
            #pragma unroll
            for (int q = 0; q < 4; ++q) {
                const float* fp = fd + (size_t)(4 * t + q) * 512 + j8;
                const float* cp = c_child + (size_t)(4 * t + q) * 512 + j8;
                floatx4 f0 = *(const floatx4*)(fp),  f1 = *(const floatx4*)(fp + 4);
                floatx4 cv0 = *(const floatx4*)(cp), cv1 = *(const floatx4*)(cp + 4);
                fc0 += (wf0 + f0) * cv0;
                fc1 += (wf1 + f1) * cv1;
            }
        }
        floatx4 cn0, cn1, hn0, hn1;
        #pragma unroll
        for (int c = 0; c < 4; ++c) {
            float ig = 1.f / (1.f + expf(-iv0[c]));
            float og = 1.f / (1.f + expf(-ov0[c]));
            float ug = tanhf(uv0[c]);
            float cv2 = ig * ug + fc0[c];
            cn0[c] = cv2;
            hn0[c] = og * tanhf(cv2);
        }
        #pragma unroll
        for (int c = 0; c < 4; ++c) {
            float ig = 1.f / (1.f + expf(-iv1[c]));
            float og = 1.f / (1.f + expf(-ov1[c]));
            float ug = tanhf(uv1[c]);
            float cv2 = ig * ug + fc1[c];
            cn1[c] = cv2;
            hn1[c] = og * tanhf(cv2);
        }
        float* cop = c_out + (size_t)n * 512 + j8;
        float* hop = h_out + (size_t)n * 512 + j8;
        *(floatx4*)(cop)     = cn0;  *(floatx4*)(cop + 4) = cn1;
        *(floatx4*)(hop)     = hn0;  *(floatx4*)(hop + 4) = hn1;
        ushort4 hb0, hb1;
        hb0.x = f2bf(hn0[0]); hb0.y = f2bf(hn0[1]); hb0.z = f2bf(hn0[2]); hb0.w = f2bf(hn0[3]);
        hb1.x = f2bf(hn1[0]); hb1.y = f2bf(hn1[1]); hb1.z = f2bf(hn1[2]); hb1.w = f2bf(hn1[3]);
        *(ushort4*)(h_bf + (size_t)n * 512 + j8)     = hb0;
        *(ushort4*)(h_bf + (size_t)n * 512 + j8 + 4) = hb1;

        hsbuf[k * 128 + jg * 2]     = hn0;
        hsbuf[k * 128 + jg * 2 + 1] = hn1;
        __syncthreads();
        if (threadIdx.x < 64) {
            const int g = threadIdx.x;
            floatx4 s0 = hsbuf[g*2]   + hsbuf[128 + g*2]   + hsbuf[256 + g*2]   + hsbuf[384 + g*2];
            floatx4 s1 = hsbuf[g*2+1] + hsbuf[128 + g*2+1] + hsbuf[256 + g*2+1] + hsbuf[384 + g*2+1];
            ushort4 o0, o1;
            o0.x = f2bf(s0[0]); o0.y = f2bf(s0[1]); o0.z = f2bf(s0[2]); o0.w = f2bf(s0[3]);
            o1.x = f2bf(s1[0]); o1.y = f2bf(s1[1]); o1.z = f2bf(s1[2]); o1.w = f2bf(s1[3]);
            *(ushort4*)(hs_bf + (size_t)tp * 512 + g * 8)     = o0;
            *(ushort4*)(hs_bf + (size_t)tp * 512 + g * 8 + 4) = o1;
        }
        __syncthreads();
    }
}

// ======================================================================================
// MEGA KERNEL v4: 7 fan-out grid barriers + 16-block tail for levels 3..0.
// vs round-3: single-flag detection (~35us rotation of ~1000 pollers on one line)
// replaced by 32-line flag broadcast (<=32 pollers/line, ~1us detection).
// ======================================================================================
__global__ __launch_bounds__(256, 2) void mega_kernel(
    const float* __restrict__ x,
    const float* __restrict__ W_iou, const float* __restrict__ b_iou,
    const float* __restrict__ W_f,   const float* __restrict__ b_f,
    const float* __restrict__ U_iou, const float* __restrict__ U_f,
    float* __restrict__ h_out, float* __restrict__ c_out,
    float* __restrict__ wx_iou, float* __restrict__ wx_f,
    float* __restrict__ ioud, float* __restrict__ fd,
    unsigned short* __restrict__ xb,
    unsigned short* __restrict__ Wib, unsigned short* __restrict__ Wfb,
    unsigned short* __restrict__ Uib, unsigned short* __restrict__ Ufb,
    unsigned short* __restrict__ h_bf, unsigned short* __restrict__ hs_bf,
    unsigned* bar)
{
    const int NB = (int)gridDim.x;
    const size_t tid0 = (size_t)blockIdx.x * 256 + threadIdx.x;
    const size_t gstr = (size_t)NB * 256;

    // ---- P0: cast xb / Wib / Wfb (only operands P1 needs) ----
    {
        const size_t C0 = (size_t)N_INT * 512 / 4;
        const size_t C1 = C0 + 1536 * 512 / 4;
        const size_t C2 = C1 + 512 * 512 / 4;
        for (size_t k = tid0; k < C2; k += gstr) {
            const float* src; size_t off;
            if (k < C0)      { src = x;     off = k; }
            else if (k < C1) { src = W_iou; off = k - C0; }
            else             { src = W_f;   off = k - C1; }
            float4 v = ((const float4*)src)[off];
            ushort4 o;
            o.x = f2bf(v.x); o.y = f2bf(v.y); o.z = f2bf(v.z); o.w = f2bf(v.w);
            ((ushort4*)xb)[k] = o;
        }
    }
    grid_bar(bar, 1);

    // ---- P1: W-GEMMs (560 tile jobs); idle blocks (b>=560) cast U_iou/U_f ----
    for (int b = blockIdx.x; b < 560; b += NB) {
        if (b < 516)
            gemm_tile_128(xb, N_INT, Wib, b_iou, wx_iou, 1536, (b / 12) * 128, (b % 12) * 128);
        else {
            int b2 = b - 516;
            gemm_tile_128(xb, 1365, Wfb, b_f, wx_f, 512, (b2 / 4) * 128, (b2 % 4) * 128);
        }
    }
    {
        const size_t CU0 = 1536 * 512 / 4;
        const size_t CU1 = CU0 + 512 * 512 / 4;
        const int nIdle = NB - 560;
        if (nIdle > 0) {
            if (blockIdx.x >= 560) {
                size_t base = (size_t)(blockIdx.x - 560) * 256 + threadIdx.x;
                for (size_t k = base; k < CU1; k += (size_t)nIdle * 256) {
                    const float* src = (k < CU0) ? U_iou : U_f;
                    size_t off = (k < CU0) ? k : k - CU0;
                    float4 v = ((const float4*)src)[off];
                    ushort4 o;
                    o.x = f2bf(v.x); o.y = f2bf(v.y); o.z = f2bf(v.z); o.w = f2bf(v.w);
                    ((ushort4*)Uib)[k] = o;
                }
            }
        } else {
            for (size_t k = tid0; k < CU1; k += gstr) {
                const float* src = (k < CU0) ? U_iou : U_f;
                size_t off = (k < CU0) ? k : k - CU0;
                float4 v = ((const float4*)src)[off];
                ushort4 o;
                o.x = f2bf(v.x); o.y = f2bf(v.y); o.z = f2bf(v.z); o.w = f2bf(v.w);
                ((ushort4*)Uib)[k] = o;
            }
        }
    }
    grid_bar(bar, 2);

    // ---- P2: combine level 6 (children are leaves, no U terms) ----
    combine_level_256(wx_iou, nullptr, nullptr, nullptr, nullptr,
                      h_out, c_out, h_bf, hs_bf, 1365, 1024, 0, NB);
    grid_bar(bar, 3);

    // ---- P3: level-5 U-GEMMs (224 tile jobs) ----
    for (int b = blockIdx.x; b < 224; b += NB) {
        if (b < 96)
            gemm_tile_128(hs_bf, 1024, Uib, nullptr, ioud, 1536, (b / 12) * 128, (b % 12) * 128);
        else {
            int b2 = b - 96;
            gemm_tile_128(h_bf + (size_t)1365 * HID, 4096, Ufb, nullptr, fd, 512,
                          (b2 / 4) * 128, (b2 % 4) * 128);
        }
    }
    grid_bar(bar, 4);

    // ---- P4: combine level 5 ----
    combine_level_256(wx_iou, wx_f, ioud, fd, c_out + (size_t)1365 * HID,
                      h_out, c_out, h_bf, hs_bf, 341, 256, 1, NB);
    grid_bar(bar, 5);

    // ---- P5: level-4 U-GEMMs (56 tile jobs) ----
    for (int b = blockIdx.x; b < 56; b += NB) {
        if (b < 24)
            gemm_tile_128(hs_bf, 256, Uib, nullptr, ioud, 1536, (b / 12) * 128, (b % 12) * 128);
        else {
            int b2 = b - 24;
            gemm_tile_128(h_bf + (size_t)341 * HID, 1024, Ufb, nullptr, fd, 512,
                          (b2 / 4) * 128, (b2 % 4) * 128);
        }
    }
    grid_bar(bar, 6);

    // ---- P6: combine level 4 ----
    combine_level_256(wx_iou, wx_f, ioud, fd, c_out + (size_t)341 * HID,
                      h_out, c_out, h_bf, hs_bf, 85, 64, 1, NB);
    grid_bar(bar, 7);

    if (blockIdx.x < 16) {
        // ---- tail: levels 3..1 + root, 16 blocks, sub-barriers only ----
        small_gemm_phase(hs_bf, h_bf + (size_t)85 * HID, Uib, Ufb, ioud, fd, 64, 16);
        tail_bar(bar, 1);
        combine_level_256(wx_iou, wx_f, ioud, fd, c_out + (size_t)85 * HID,
                          h_out, c_out, h_bf, hs_bf, 21, 16, 1, 16);
        tail_bar(bar, 2);
        small_gemm_phase(hs_bf, h_bf + (size_t)21 * HID, Uib, Ufb, ioud, fd, 16, 16);
        tail_bar(bar, 3);
        combine_level_256(wx_iou, wx_f, ioud, fd, c_out + (size_t)21 * HID,
                          h_out, c_out, h_bf, hs_bf, 5, 4, 1, 16);
        tail_bar(bar, 4);
        small_gemm_phase(hs_bf, h_bf + (size_t)5 * HID, Uib, Ufb, ioud, fd, 4, 16);
        tail_bar(bar, 5);
        combine_level_256(wx_iou, wx_f, ioud, fd, c_out + (size_t)5 * HID,
                          h_out, c_out, h_bf, hs_bf, 1, 1, 1, 16);
        tail_bar(bar, 6);
        small_gemm_phase(hs_bf, h_bf + (size_t)1 * HID, Uib, Ufb, ioud, fd, 1, 16);
        tail_bar(bar, 7);
        // root combine (node 0): block 0, 256 threads x 2 elems
        if (blockIdx.x == 0) {
            const int j = threadIdx.x * 2;
            #pragma unroll
            for (int c = 0; c < 2; ++c) {
                const int jj = j + c;
                float iv = wx_iou[jj]        + ioud[jj];
                float ov = wx_iou[512 + jj]  + ioud[512 + jj];
                float uv = wx_iou[1024 + jj] + ioud[1024 + jj];
                float wf = wx_f[jj];
                float fc = 0.f;
                #pragma unroll
                for (int q = 0; q < 4; ++q)
                    fc += (wf + fd[(size_t)q * 512 + jj]) * c_out[(size_t)(q + 1) * 512 + jj];
                float ig = 1.f / (1.f + expf(-iv));
                float og = 1.f / (1.f + expf(-ov));
                float ug = tanhf(uv);
                float cv2 = ig * ug + fc;
                c_out[jj] = cv2;
                h_out[jj] = og * tanhf(cv2);
            }
        }
    } else {
        // ---- leaf h/c zeroing (no consumer), overlaps the tail ----
        float4* hleaf = (float4*)(h_out + (size_t)N_INT * HID);
        float4* cleaf = (float4*)(c_out + (size_t)N_INT * HID);
        const size_t Z = (size_t)(N_NODES - N_INT) * HID / 4;
        const float4 zz = {0.f, 0.f, 0.f, 0.f};
        size_t base = (size_t)(blockIdx.x - 16) * 256 + threadIdx.x;
        const size_t zstr = (size_t)(NB - 16) * 256;
        for (size_t i = base; i < 2 * Z; i += zstr) {
            if (i < Z) hleaf[i] = zz;
            else       cleaf[i - Z] = zz;
        }
    }
}

// ======================================================================================
// Fallback multi-dispatch path (verified 275 us version), if cooperative launch fails.
// ======================================================================================
__global__ void prep_kernel(const float* __restrict__ x,
                            const float* __restrict__ W_iou,
                            const float* __restrict__ W_f,
                            const float* __restrict__ U_iou,
                            const float* __restrict__ U_f,
                            float* __restrict__ h_leaf,
                            float* __restrict__ c_leaf,
                            unsigned short* __restrict__ dstb)
{
    prep_body(x, W_iou, W_f, U_iou, U_f, h_leaf, c_leaf, dstb);
}

__global__ __launch_bounds__(256) void wgemm_kernel(
    const unsigned short* __restrict__ xb,
    const unsigned short* __restrict__ Wib,
    const unsigned short* __restrict__ Wfb,
    const float* __restrict__ b_iou, const float* __restrict__ b_f,
    float* __restrict__ wx_iou, float* __restrict__ wx_f)
{
    int b = blockIdx.x;
    if (b < 516) {
        gemm_tile_128(xb, N_INT, Wib, b_iou, wx_iou, 1536, (b / 12) * 128, (b % 12) * 128);
    } else {
        int b2 = b - 516;
        gemm_tile_128(xb, 1365, Wfb, b_f, wx_f, 512, (b2 / 4) * 128, (b2 % 4) * 128);
    }
}

__global__ __launch_bounds__(256) void gemm5_kernel(
    const unsigned short* __restrict__ hs_bf,
    const unsigned short* __restrict__ h6_bf,
    const unsigned short* __restrict__ Uib, const unsigned short* __restrict__ Ufb,
    float* __restrict__ ioud, float* __restrict__ fd)
{
    int b = blockIdx.x;
    if (b < 96) {
        gemm_tile_128(hs_bf, 1024, Uib, nullptr, ioud, 1536, (b / 12) * 128, (b % 12) * 128);
    } else {
        int b2 = b - 96;
        gemm_tile_128(h6_bf, 4096, Ufb, nullptr, fd, 512, (b2 / 4) * 128, (b2 % 4) * 128);
    }
}

__global__ __launch_bounds__(256) void gemm4_kernel(
    const unsigned short* __restrict__ hs_bf,
    const unsigned short* __restrict__ h5_bf,
    const unsigned short* __restrict__ Uib, const unsigned short* __restrict__ Ufb,
    float* __restrict__ ioud, float* __restrict__ fd)
{
    int b = blockIdx.x;
    if (b < 24) {
        gemm_tile_128(hs_bf, 256, Uib, nullptr, ioud, 1536, (b / 12) * 128, (b % 12) * 128);
    } else {
        int b2 = b - 24;
        gemm_tile_128(h5_bf, 1024, Ufb, nullptr, fd, 512, (b2 / 4) * 128, (b2 % 4) * 128);
    }
}

__global__ __launch_bounds__(256) void gemm_small_kernel(
    const unsigned short* __restrict__ hs_bf,
    const unsigned short* __restrict__ hch_bf,
    const unsigned short* __restrict__ Uib, const unsigned short* __restrict__ Ufb,
    float* __restrict__ ioud, float* __restrict__ fd, int nl)
{
    const int w = blockIdx.x * 4 + (threadIdx.x >> 6);
    const int mI = (nl + 15) >> 4;
    const int mF = (4 * nl + 15) >> 4;
    if (w < mI * 24) {
        direct_tile_16x64(hs_bf, nl, Uib, ioud, 1536, (w / 24) * 16, (w % 24) * 64);
    } else {
        int w2 = w - mI * 24;
        if (w2 < mF * 8)
            direct_tile_16x64(hch_bf, 4 * nl, Ufb, fd, 512, (w2 / 8) * 16, (w2 % 8) * 64);
    }
}

__global__ __launch_bounds__(256) void combine_kernel_fb(
    const float* __restrict__ wx_iou, const float* __restrict__ wx_f,
    const float* __restrict__ ioud, const float* __restrict__ fd,
    const float* __restrict__ c_child,
    float* __restrict__ h_out, float* __restrict__ c_out,
    unsigned short* __restrict__ h_bf, unsigned short* __restrict__ hs_bf,
    int s, int np, int hasU)
{
    combine_level_256(wx_iou, wx_f, ioud, fd, c_child, h_out, c_out, h_bf, hs_bf,
                      s, np, hasU, (int)gridDim.x);
}

__global__ __launch_bounds__(128) void combine_root_kernel(
    const float* __restrict__ wx_iou, const float* __restrict__ wx_f,
    const float* __restrict__ ioud, const float* __restrict__ fd,
    const float* __restrict__ c_child,
    float* __restrict__ h_out, float* __restrict__ c_out)
{
    const int j4 = threadIdx.x << 2;
    #pragma unroll
    for (int c = 0; c < 4; ++c) {
        const int jj = j4 + c;
        float iv = wx_iou[jj]        + ioud[jj];
        float ov = wx_iou[512 + jj]  + ioud[512 + jj];
        float uv = wx_iou[1024 + jj] + ioud[1024 + jj];
        float wf = wx_f[jj];
        float fc = 0.f;
        #pragma unroll
        for (int q = 0; q < 4; ++q)
            fc += (wf + fd[(size_t)q * 512 + jj]) * c_child[(size_t)q * 512 + jj];
        float ig = 1.f / (1.f + expf(-iv));
        float og = 1.f / (1.f + expf(-ov));
        float ug = tanhf(uv);
        float cv2 = ig * ug + fc;
        c_out[jj] = cv2;
        h_out[jj] = og * tanhf(cv2);
    }
}

extern "C" void kernel_launch(void* const* d_in, const int* in_sizes, int n_in,
                              void* d_out, int out_size, void* d_ws, size_t ws_size,
                              hipStream_t stream) {
    const float* x     = (const float*)d_in[0];
    // d_in[1] = children: deterministic (4n+1..4n+4), not needed
    const float* W_iou = (const float*)d_in[2];
    const float* b_iou = (const float*)d_in[3];
    const float* W_f   = (const float*)d_in[4];
    const float* b_f   = (const float*)d_in[5];
    const float* U_iou = (const float*)d_in[6];
    const float* U_f   = (const float*)d_in[7];

    float* h_out = (float*)d_out;                       // N_NODES x 512
    float* c_out = h_out + (size_t)N_NODES * HID;       // N_NODES x 512

    // ---- workspace layout (fp32 region, then contiguous bf16 cast region) ----
    float* ws     = (float*)d_ws;
    float* wx_iou = ws;                                  // 5461*1536 f32
    float* wx_f   = wx_iou + (size_t)N_INT * 1536;       // 1365*512  f32
    float* ioud   = wx_f   + (size_t)1365 * 512;         // 1024*1536 f32
    float* fd     = ioud   + (size_t)1024 * 1536;        // 4096*512  f32
    unsigned short* xb   = (unsigned short*)(fd + (size_t)4096 * 512);
    unsigned short* Wib  = xb  + (size_t)N_INT * 512;    // 1536*512 bf16
    unsigned short* Wfb  = Wib + (size_t)1536 * 512;     // 512*512
    unsigned short* Uib  = Wfb + (size_t)512 * 512;      // 1536*512
    unsigned short* Ufb  = Uib + (size_t)1536 * 512;     // 512*512
    unsigned short* h_bf = Ufb + (size_t)512 * 512;      // 5461*512
    unsigned short* hs_bf= h_bf + (size_t)N_INT * 512;   // 1024*512
    unsigned* bar = (unsigned*)(hs_bf + (size_t)1024 * 512);  // barrier lines (~8.6 KB)

    // ---- cooperative mega-kernel path ----
    static int coopGrid = -1;   // -1 unknown, 0 disabled, >0 grid size
    if (coopGrid == -1) {
        int nb = 0;
        hipError_t qe = hipOccupancyMaxActiveBlocksPerMultiprocessor(&nb, mega_kernel, 256, 0);
        if (qe == hipSuccess && nb >= 1) {
            if (nb > 4) nb = 4;
            coopGrid = nb * 256;             // multiple of 32 (barrier groups)
        } else {
            coopGrid = 0;
            (void)hipGetLastError();
        }
    }

    bool launched = false;
    if (coopGrid > 0) {
        hipError_t em = hipMemsetAsync(bar, 0, 8704, stream);   // ws re-poisoned each iter
        if (em == hipSuccess) {
            void* args[] = { (void*)&x, (void*)&W_iou, (void*)&b_iou, (void*)&W_f, (void*)&b_f,
                             (void*)&U_iou, (void*)&U_f, (void*)&h_out, (void*)&c_out,
                             (void*)&wx_iou, (void*)&wx_f, (void*)&ioud, (void*)&fd,
                             (void*)&xb, (void*)&Wib, (void*)&Wfb, (void*)&Uib, (void*)&Ufb,
                             (void*)&h_bf, (void*)&hs_bf, (void*)&bar };
            hipError_t e = hipLaunchCooperativeKernel((const void*)mega_kernel,
                                                      dim3(coopGrid), dim3(256), args, 0, stream);
            if (e == hipSuccess) {
                launched = true;
            } else {
                coopGrid = 0;
                (void)hipGetLastError();
            }
        } else {
            coopGrid = 0;
            (void)hipGetLastError();
        }
    }

    if (!launched) {
        // ---- previous verified 17-dispatch path ----
        prep_kernel<<<2048, 256, 0, stream>>>(x, W_iou, W_f, U_iou, U_f,
                                              h_out + (size_t)N_INT * HID,
                                              c_out + (size_t)N_INT * HID, xb);
        wgemm_kernel<<<516 + 44, 256, 0, stream>>>(xb, Wib, Wfb, b_iou, b_f, wx_iou, wx_f);
        combine_kernel_fb<<<1024, 256, 0, stream>>>(
            wx_iou, nullptr, nullptr, nullptr, nullptr,
            h_out, c_out, h_bf, hs_bf, 1365, 1024, 0);
        gemm5_kernel<<<224, 256, 0, stream>>>(hs_bf, h_bf + (size_t)1365 * HID, Uib, Ufb, ioud, fd);
        combine_kernel_fb<<<256, 256, 0, stream>>>(
            wx_iou, wx_f, ioud, fd, c_out + (size_t)1365 * HID,
            h_out, c_out, h_bf, hs_bf, 341, 256, 1);
        gemm4_kernel<<<56, 256, 0, stream>>>(hs_bf, h_bf + (size_t)341 * HID, Uib, Ufb, ioud, fd);
        combine_kernel_fb<<<64, 256, 0, stream>>>(
            wx_iou, wx_f, ioud, fd, c_out + (size_t)341 * HID,
            h_out, c_out, h_bf, hs_bf, 85, 64, 1);
        const int offs[9] = {0, 1, 5, 21, 85, 341, 1365, 5461, 21845};
        for (int l = 3; l >= 1; --l) {
            const int s  = offs[l];
            const int nl = offs[l + 1] - s;
            const int cb = offs[l + 1];
            const int mI = (nl + 15) >> 4;
            const int mF = (4 * nl + 15) >> 4;
            const int waves = mI * 24 + mF * 8;
            gemm_small_kernel<<<(waves + 3) / 4, 256, 0, stream>>>(
                hs_bf, h_bf + (size_t)cb * HID, Uib, Ufb, ioud, fd, nl);
            combine_kernel_fb<<<(nl + 3) / 4, 256, 0, stream>>>(
                wx_iou, wx_f, ioud, fd, c_out + (size_t)cb * HID,
                h_out, c_out, h_bf, hs_bf, s, nl >> 2, 1);
        }
        gemm_small_kernel<<<8, 256, 0, stream>>>(
            hs_bf, h_bf + (size_t)1 * HID, Uib, Ufb, ioud, fd, 1);
        combine_root_kernel<<<1, 128, 0, stream>>>(
            wx_iou, wx_f, ioud, fd, c_out + (size_t)1 * HID, h_out, c_out);
    }
}

// Round 5
// 283.639 us; speedup vs baseline: 2.4834x; 1.5167x over previous
//
#include <hip/hip_runtime.h>
#include <cmath>

// Tree constants (complete 4-ary tree, depth 7)
constexpr int N_NODES = 21845;
constexpr int N_INT   = 5461;   // internal nodes (levels 0..6)
constexpr int HID     = 512;

typedef short  short8  __attribute__((ext_vector_type(8)));
typedef float  floatx4 __attribute__((ext_vector_type(4)));

// fp32 -> bf16 bit pattern, round-to-nearest-even
__device__ __forceinline__ unsigned short f2bf(float f) {
    unsigned int u = __float_as_uint(f);
    u += 0x7fffu + ((u >> 16) & 1u);
    return (unsigned short)(u >> 16);
}

#define GLD_LDS(g, l) __builtin_amdgcn_global_load_lds( \
    (const __attribute__((address_space(1))) void*)(g), \
    (__attribute__((address_space(3))) void*)(l), 16, 0, 0)

// ================= grid barrier (SMALL grids only) =================
// Rounds 2-4 evidence: full-grid (1024-block) barriers cost ~35us regardless of
// arrival/detection structure -> cost is the ~per-block-leader L2 cache-maintenance
// (wbl2/inv tag walks), ~128 leaders/XCD. At <=64 blocks (<=8 leaders/XCD) the same
// barrier is ~2-4us, which BEATS a dispatch boundary (~5-7us under graph replay).
// Strategy: dispatch boundaries for wide phases, in-kernel barriers for narrow ones.
__device__ __forceinline__ void grid_bar(unsigned* bars, unsigned phase) {
    __syncthreads();
    if (threadIdx.x == 0) {
        const unsigned g   = blockIdx.x & 31;
        const unsigned gsz = gridDim.x >> 5;          // NB is a multiple of 32
        unsigned* gcnt  = bars + g * 32;
        unsigned* gflag = bars + 1024 + g * 32;
        unsigned r = __hip_atomic_fetch_add(gcnt, 1u, __ATOMIC_ACQ_REL, __HIP_MEMORY_SCOPE_AGENT);
        if (r == phase * gsz - 1u) {
            unsigned rr = __hip_atomic_fetch_add(bars + 2048, 1u, __ATOMIC_ACQ_REL,
                                                 __HIP_MEMORY_SCOPE_AGENT);
            if (rr == phase * 32u - 1u) {
                __builtin_amdgcn_fence(__ATOMIC_RELEASE, "agent");
                #pragma unroll
                for (int i = 0; i < 32; ++i)
                    __hip_atomic_store(bars + 1024 + i * 32, phase, __ATOMIC_RELAXED,
                                       __HIP_MEMORY_SCOPE_AGENT);
            }
        }
        while (__hip_atomic_load(gflag, __ATOMIC_RELAXED, __HIP_MEMORY_SCOPE_AGENT) < phase)
            __builtin_amdgcn_s_sleep(2);
        __builtin_amdgcn_fence(__ATOMIC_ACQUIRE, "agent");
    }
    __syncthreads();
}

// 16-block sub-barrier (blocks 0..15 only) — validated in rounds 3-4
__device__ __forceinline__ void tail_bar(unsigned* bars, unsigned phase) {
    __syncthreads();
    if (threadIdx.x == 0) {
        unsigned* cnt  = bars + 2080;
        unsigned* flag = bars + 2112;
        unsigned r = __hip_atomic_fetch_add(cnt, 1u, __ATOMIC_ACQ_REL, __HIP_MEMORY_SCOPE_AGENT);
        if (r == phase * 16u - 1u)
            __hip_atomic_store(flag, phase, __ATOMIC_RELEASE, __HIP_MEMORY_SCOPE_AGENT);
        while (__hip_atomic_load(flag, __ATOMIC_RELAXED, __HIP_MEMORY_SCOPE_AGENT) < phase)
            __builtin_amdgcn_s_sleep(2);
        __builtin_amdgcn_fence(__ATOMIC_ACQUIRE, "agent");
    }
    __syncthreads();
}

// ================= prep (fallback path): zero leaves + cast all =================
__device__ __forceinline__ void prep_body(const float* __restrict__ x,
                                          const float* __restrict__ W_iou,
                                          const float* __restrict__ W_f,
                                          const float* __restrict__ U_iou,
                                          const float* __restrict__ U_f,
                                          float* __restrict__ h_leaf,
                                          float* __restrict__ c_leaf,
                                          unsigned short* __restrict__ dstb)
{
    const size_t Z  = (size_t)(N_NODES - N_INT) * HID / 4;
    const size_t C0 = (size_t)N_INT * 512 / 4;
    const size_t C1 = C0 + 1536 * 512 / 4;
    const size_t C2 = C1 + 512 * 512 / 4;
    const size_t C3 = C2 + 1536 * 512 / 4;
    const size_t C4 = C3 + 512 * 512 / 4;
    const size_t total = 2 * Z + C4;
    size_t i = (size_t)blockIdx.x * blockDim.x + threadIdx.x;
    const size_t stride = (size_t)gridDim.x * blockDim.x;
    const float4 zz = {0.f, 0.f, 0.f, 0.f};
    for (; i < total; i += stride) {
        if (i < 2 * Z) {
            if (i < Z) ((float4*)h_leaf)[i] = zz;
            else       ((float4*)c_leaf)[i - Z] = zz;
        } else {
            size_t k = i - 2 * Z;
            const float* src; size_t off;
            if (k < C0)      { src = x;     off = k; }
            else if (k < C1) { src = W_iou; off = k - C0; }
            else if (k < C2) { src = W_f;   off = k - C1; }
            else if (k < C3) { src = U_iou; off = k - C2; }
            else             { src = U_f;   off = k - C3; }
            float4 v = ((const float4*)src)[off];
            ushort4 o;
            o.x = f2bf(v.x); o.y = f2bf(v.y); o.z = f2bf(v.z); o.w = f2bf(v.w);
            ((ushort4*)dstb)[k] = o;
        }
    }
}

// cast-only prep (main path; leaf zeroing moved into tail kernel)
__global__ void prep_cast_kernel(const float* __restrict__ x,
                                 const float* __restrict__ W_iou,
                                 const float* __restrict__ W_f,
                                 const float* __restrict__ U_iou,
                                 const float* __restrict__ U_f,
                                 unsigned short* __restrict__ dstb)
{
    const size_t C0 = (size_t)N_INT * 512 / 4;
    const size_t C1 = C0 + 1536 * 512 / 4;
    const size_t C2 = C1 + 512 * 512 / 4;
    const size_t C3 = C2 + 1536 * 512 / 4;
    const size_t C4 = C3 + 512 * 512 / 4;
    size_t i = (size_t)blockIdx.x * blockDim.x + threadIdx.x;
    const size_t stride = (size_t)gridDim.x * blockDim.x;
    for (; i < C4; i += stride) {
        const float* src; size_t off;
        if (i < C0)      { src = x;     off = i; }
        else if (i < C1) { src = W_iou; off = i - C0; }
        else if (i < C2) { src = W_f;   off = i - C1; }
        else if (i < C3) { src = U_iou; off = i - C2; }
        else             { src = U_f;   off = i - C3; }
        float4 v = ((const float4*)src)[off];
        ushort4 o;
        o.x = f2bf(v.x); o.y = f2bf(v.y); o.z = f2bf(v.z); o.w = f2bf(v.w);
        ((ushort4*)dstb)[i] = o;
    }
}

// ================= 128x128 bf16 MFMA GEMM tile (K=512), m97-style =================
__device__ __forceinline__ void gemm_tile_128(
    const unsigned short* __restrict__ A, int Arows,
    const unsigned short* __restrict__ B,
    const float* __restrict__ bias,
    float* __restrict__ C, int ldc,
    int bm, int bn)
{
    __shared__ short8 AsV[1024];   // 128 rows x 8 chunks (16B) = 16 KB
    __shared__ short8 BsV[1024];

    const int tid  = threadIdx.x;
    const int wave = tid >> 6;
    const int lane = tid & 63;
    const int quad = lane >> 4;
    const int lr   = lane & 15;
    const int wr = (wave >> 1) * 64;
    const int wc = (wave & 1) * 64;

    floatx4 acc[4][4];
    #pragma unroll
    for (int i = 0; i < 4; ++i)
        #pragma unroll
        for (int j = 0; j < 4; ++j)
            acc[i][j] = (floatx4){0.f, 0.f, 0.f, 0.f};

    int s_row[4], s_gk[4];
    #pragma unroll
    for (int it = 0; it < 4; ++it) {
        int c = it * 256 + wave * 64 + lane;
        s_row[it] = c >> 3;
        s_gk[it]  = (c & 7) ^ (s_row[it] & 7);
    }

    for (int k0 = 0; k0 < 512; k0 += 64) {
        #pragma unroll
        for (int it = 0; it < 4; ++it) {
            int row = s_row[it];
            int gm = bm + row; if (gm >= Arows) gm = Arows - 1;
            GLD_LDS(A + (size_t)gm * 512 + k0 + s_gk[it] * 8, &AsV[it * 256 + wave * 64]);
            int gn = bn + row;
            GLD_LDS(B + (size_t)gn * 512 + k0 + s_gk[it] * 8, &BsV[it * 256 + wave * 64]);
        }
        __syncthreads();

        #pragma unroll
        for (int kc = 0; kc < 2; ++kc) {
            short8 af[4], bfr[4];
            const int q = kc * 4 + quad;
            #pragma unroll
            for (int mt = 0; mt < 4; ++mt) {
                int row = wr + mt * 16 + lr;
                af[mt] = AsV[row * 8 + (q ^ (row & 7))];
            }
            #pragma unroll
            for (int nt = 0; nt < 4; ++nt) {
                int row = wc + nt * 16 + lr;
                bfr[nt] = BsV[row * 8 + (q ^ (row & 7))];
            }
            #pragma unroll
            for (int mt = 0; mt < 4; ++mt)
                #pragma unroll
                for (int nt = 0; nt < 4; ++nt)
                    acc[mt][nt] = __builtin_amdgcn_mfma_f32_16x16x32_bf16(
                        af[mt], bfr[nt], acc[mt][nt], 0, 0, 0);
        }
        __syncthreads();
    }

    #pragma unroll
    for (int mt = 0; mt < 4; ++mt) {
        #pragma unroll
        for (int r = 0; r < 4; ++r) {
            int gm = bm + wr + mt * 16 + quad * 4 + r;
            if (gm >= Arows) continue;
            #pragma unroll
            for (int nt = 0; nt < 4; ++nt) {
                int gn = bn + wc + nt * 16 + lr;
                float v = acc[mt][nt][r];
                if (bias) v += bias[gn];
                C[(size_t)gm * ldc + gn] = v;
            }
        }
    }
}

// ================= direct-from-global MFMA GEMM for tiny levels =================
__device__ __forceinline__ void direct_tile_16x64(
    const unsigned short* __restrict__ A, int Arows,
    const unsigned short* __restrict__ B,
    float* __restrict__ C, int ldc,
    int m0, int n0)
{
    const int lane = threadIdx.x & 63;
    const int quad = lane >> 4;
    const int lr   = lane & 15;
    int am = m0 + lr; if (am >= Arows) am = Arows - 1;   // clamp (store-masked)
    const unsigned short* ap = A + (size_t)am * 512 + quad * 8;
    const unsigned short* bp = B + (size_t)(n0 + lr) * 512 + quad * 8;

    floatx4 acc[4];
    #pragma unroll
    for (int j = 0; j < 4; ++j) acc[j] = (floatx4){0.f, 0.f, 0.f, 0.f};

    #pragma unroll
    for (int k0 = 0; k0 < 512; k0 += 32) {
        short8 af = *(const short8*)(ap + k0);
        #pragma unroll
        for (int j = 0; j < 4; ++j) {
            short8 bf = *(const short8*)(bp + (size_t)j * 16 * 512 + k0);
            acc[j] = __builtin_amdgcn_mfma_f32_16x16x32_bf16(af, bf, acc[j], 0, 0, 0);
        }
    }

    #pragma unroll
    for (int j = 0; j < 4; ++j) {
        #pragma unroll
        for (int r = 0; r < 4; ++r) {
            int gm = m0 + quad * 4 + r;
            if (gm < Arows) C[(size_t)gm * ldc + n0 + j * 16 + lr] = acc[j][r];
        }
    }
}

// ================= small-level U-GEMMs (grid-stride over 16x64 wave tiles) =================
__device__ __forceinline__ void small_gemm_phase(
    const unsigned short* __restrict__ hs_bf,
    const unsigned short* __restrict__ hch_bf,
    const unsigned short* __restrict__ Uib, const unsigned short* __restrict__ Ufb,
    float* __restrict__ ioud, float* __restrict__ fd, int nl, int nbsub)
{
    const int mI = (nl + 15) >> 4;
    const int mF = (4 * nl + 15) >> 4;
    const int totW = mI * 24 + mF * 8;
    for (int w = blockIdx.x * 4 + (threadIdx.x >> 6); w < totW; w += nbsub * 4) {
        if (w < mI * 24)
            direct_tile_16x64(hs_bf, nl, Uib, ioud, 1536, (w / 24) * 16, (w % 24) * 64);
        else {
            int w2 = w - mI * 24;
            direct_tile_16x64(hch_bf, 4 * nl, Ufb, fd, 512, (w2 / 8) * 16, (w2 % 8) * 64);
        }
    }
}

// ================= 256-thread combine: 4 siblings/parent group, 8 hid elems/thread ========
__device__ void combine_level_256(
    const float* __restrict__ wx_iou, const float* __restrict__ wx_f,
    const float* __restrict__ ioud, const float* __restrict__ fd,
    const float* __restrict__ c_child,
    float* __restrict__ h_out, float* __restrict__ c_out,
    unsigned short* __restrict__ h_bf, unsigned short* __restrict__ hs_bf,
    int s, int np, int hasU, int nbsub)
{
    __shared__ floatx4 hsbuf[512];   // 8 KB
    const int k  = threadIdx.x >> 6;
    const int jg = threadIdx.x & 63;
    const int j8 = jg << 3;

    for (int tp = blockIdx.x; tp < np; tp += nbsub) {
        const int t = 4 * tp + k;
        const int n = s + t;
        const float* wrow = wx_iou + (size_t)n * 1536 + j8;
        floatx4 iv0 = *(const floatx4*)(wrow);
        floatx4 iv1 = *(const floatx4*)(wrow + 4);
        floatx4 ov0 = *(const floatx4*)(wrow + 512);
        floatx4 ov1 = *(const floatx4*)(wrow + 516);
        floatx4 uv0 = *(const floatx4*)(wrow + 1024);
        floatx4 uv1 = *(const floatx4*)(wrow + 1028);
        floatx4 fc0 = (floatx4){0.f,0.f,0.f,0.f};
        floatx4 fc1 = (floatx4){0.f,0.f,0.f,0.f};
        if (hasU) {
            const float* drow = ioud + (size_t)t * 1536 + j8;
            iv0 += *(const floatx4*)(drow);        iv1 += *(const floatx4*)(drow + 4);
            ov0 += *(const floatx4*)(drow + 512);  ov1 += *(const floatx4*)(drow + 516);
            uv0 += *(const floatx4*)(drow + 1024); uv1 += *(const floatx4*)(drow + 1028);
            const float* wfp = wx_f + (size_t)n * 512 + j8;
            floatx4 wf0 = *(const floatx4*)(wfp);
            floatx4 wf1 = *(const floatx4*)(wfp + 4);
            #pragma unroll
            for (int q = 0; q < 4; ++q) {
                const float* fp = fd + (size_t)(4 * t + q) * 512 + j8;
                const float* cp = c_child + (size_t)(4 * t + q) * 512 + j8;
                floatx4 f0 = *(const floatx4*)(fp),  f1 = *(const floatx4*)(fp + 4);
                floatx4 cv0 = *(const floatx4*)(cp), cv1 = *(const floatx4*)(cp + 4);
                fc0 += (wf0 + f0) * cv0;
                fc1 += (wf1 + f1) * cv1;
            }
        }
        floatx4 cn0, cn1, hn0, hn1;
        #pragma unroll
        for (int c = 0; c < 4; ++c) {
            float ig = 1.f / (1.f + expf(-iv0[c]));
            float og = 1.f / (1.f + expf(-ov0[c]));
            float ug = tanhf(uv0[c]);
            float cv2 = ig * ug + fc0[c];
            cn0[c] = cv2;
            hn0[c] = og * tanhf(cv2);
        }
        #pragma unroll
        for (int c = 0; c < 4; ++c) {
            float ig = 1.f / (1.f + expf(-iv1[c]));
            float og = 1.f / (1.f + expf(-ov1[c]));
            float ug = tanhf(uv1[c]);
            float cv2 = ig * ug + fc1[c];
            cn1[c] = cv2;
            hn1[c] = og * tanhf(cv2);
        }
        float* cop = c_out + (size_t)n * 512 + j8;
        float* hop = h_out + (size_t)n * 512 + j8;
        *(floatx4*)(cop)     = cn0;  *(floatx4*)(cop + 4) = cn1;
        *(floatx4*)(hop)     = hn0;  *(floatx4*)(hop + 4) = hn1;
        ushort4 hb0, hb1;
        hb0.x = f2bf(hn0[0]); hb0.y = f2bf(hn0[1]); hb0.z = f2bf(hn0[2]); hb0.w = f2bf(hn0[3]);
        hb1.x = f2bf(hn1[0]); hb1.y = f2bf(hn1[1]); hb1.z = f2bf(hn1[2]); hb1.w = f2bf(hn1[3]);
        *(ushort4*)(h_bf + (size_t)n * 512 + j8)     = hb0;
        *(ushort4*)(h_bf + (size_t)n * 512 + j8 + 4) = hb1;

        hsbuf[k * 128 + jg * 2]     = hn0;
        hsbuf[k * 128 + jg * 2 + 1] = hn1;
        __syncthreads();
        if (threadIdx.x < 64) {
            const int g = threadIdx.x;
            floatx4 s0 = hsbuf[g*2]   + hsbuf[128 + g*2]   + hsbuf[256 + g*2]   + hsbuf[384 + g*2];
            floatx4 s1 = hsbuf[g*2+1] + hsbuf[128 + g*2+1] + hsbuf[256 + g*2+1] + hsbuf[384 + g*2+1];
            ushort4 o0, o1;
            o0.x = f2bf(s0[0]); o0.y = f2bf(s0[1]); o0.z = f2bf(s0[2]); o0.w = f2bf(s0[3]);
            o1.x = f2bf(s1[0]); o1.y = f2bf(s1[1]); o1.z = f2bf(s1[2]); o1.w = f2bf(s1[3]);
            *(ushort4*)(hs_bf + (size_t)tp * 512 + g * 8)     = o0;
            *(ushort4*)(hs_bf + (size_t)tp * 512 + g * 8 + 4) = o1;
        }
        __syncthreads();
    }
}

// ================= phase kernels =================
__global__ __launch_bounds__(256) void wgemm_kernel(
    const unsigned short* __restrict__ xb,
    const unsigned short* __restrict__ Wib,
    const unsigned short* __restrict__ Wfb,
    const float* __restrict__ b_iou, const float* __restrict__ b_f,
    float* __restrict__ wx_iou, float* __restrict__ wx_f)
{
    int b = blockIdx.x;
    if (b < 516) {
        gemm_tile_128(xb, N_INT, Wib, b_iou, wx_iou, 1536, (b / 12) * 128, (b % 12) * 128);
    } else {
        int b2 = b - 516;
        gemm_tile_128(xb, 1365, Wfb, b_f, wx_f, 512, (b2 / 4) * 128, (b2 % 4) * 128);
    }
}

__global__ __launch_bounds__(256) void gemm5_kernel(
    const unsigned short* __restrict__ hs_bf,
    const unsigned short* __restrict__ h6_bf,
    const unsigned short* __restrict__ Uib, const unsigned short* __restrict__ Ufb,
    float* __restrict__ ioud, float* __restrict__ fd)
{
    int b = blockIdx.x;
    if (b < 96) {
        gemm_tile_128(hs_bf, 1024, Uib, nullptr, ioud, 1536, (b / 12) * 128, (b % 12) * 128);
    } else {
        int b2 = b - 96;
        gemm_tile_128(h6_bf, 4096, Ufb, nullptr, fd, 512, (b2 / 4) * 128, (b2 % 4) * 128);
    }
}

__global__ __launch_bounds__(256) void combine_kernel_fb(
    const float* __restrict__ wx_iou, const float* __restrict__ wx_f,
    const float* __restrict__ ioud, const float* __restrict__ fd,
    const float* __restrict__ c_child,
    float* __restrict__ h_out, float* __restrict__ c_out,
    unsigned short* __restrict__ h_bf, unsigned short* __restrict__ hs_bf,
    int s, int np, int hasU)
{
    combine_level_256(wx_iou, wx_f, ioud, fd, c_child, h_out, c_out, h_bf, hs_bf,
                      s, np, hasU, (int)gridDim.x);
}

// ---- P56 cooperative: gemm4 (56 jobs) + 64-block barrier + combine4 ----
__global__ __launch_bounds__(256) void p56_kernel(
    unsigned short* hs_bf, const unsigned short* __restrict__ h5_bf,
    const unsigned short* __restrict__ Uib, const unsigned short* __restrict__ Ufb,
    float* ioud, float* fd,
    const float* __restrict__ wx_iou, const float* __restrict__ wx_f,
    float* c_out, float* h_out,
    unsigned short* h_bf,
    unsigned* bar)
{
    if (blockIdx.x < 56) {
        int b = blockIdx.x;
        if (b < 24)
            gemm_tile_128(hs_bf, 256, Uib, nullptr, ioud, 1536, (b / 12) * 128, (b % 12) * 128);
        else {
            int b2 = b - 24;
            gemm_tile_128(h5_bf, 1024, Ufb, nullptr, fd, 512, (b2 / 4) * 128, (b2 % 4) * 128);
        }
    }
    grid_bar(bar, 1);   // 64 arrivals: ~8 leaders/XCD -> cheap regime
    combine_level_256(wx_iou, wx_f, ioud, fd, c_out + (size_t)341 * HID,
                      h_out, c_out, h_bf, hs_bf, 85, 64, 1, 64);
}

// ---- TAIL cooperative: blocks 0-15 run levels 3..1 + root (tail_bar x7);
//      blocks 16+ zero leaf h/c concurrently (no consumer). ----
__global__ __launch_bounds__(256) void tail_kernel(
    unsigned short* hs_bf, unsigned short* h_bf,
    const unsigned short* __restrict__ Uib, const unsigned short* __restrict__ Ufb,
    float* ioud, float* fd,
    const float* __restrict__ wx_iou, const float* __restrict__ wx_f,
    float* h_out, float* c_out,
    unsigned* bar)
{
    if (blockIdx.x >= 16) {
        float4* hleaf = (float4*)(h_out + (size_t)N_INT * HID);
        float4* cleaf = (float4*)(c_out + (size_t)N_INT * HID);
        const size_t Z = (size_t)(N_NODES - N_INT) * HID / 4;
        const float4 zz = {0.f, 0.f, 0.f, 0.f};
        size_t base = (size_t)(blockIdx.x - 16) * 256 + threadIdx.x;
        const size_t zstr = (size_t)(gridDim.x - 16) * 256;
        for (size_t i = base; i < 2 * Z; i += zstr) {
            if (i < Z) hleaf[i] = zz;
            else       cleaf[i - Z] = zz;
        }
        return;
    }
    small_gemm_phase(hs_bf, h_bf + (size_t)85 * HID, Uib, Ufb, ioud, fd, 64, 16);
    tail_bar(bar, 1);
    combine_level_256(wx_iou, wx_f, ioud, fd, c_out + (size_t)85 * HID,
                      h_out, c_out, h_bf, hs_bf, 21, 16, 1, 16);
    tail_bar(bar, 2);
    small_gemm_phase(hs_bf, h_bf + (size_t)21 * HID, Uib, Ufb, ioud, fd, 16, 16);
    tail_bar(bar, 3);
    combine_level_256(wx_iou, wx_f, ioud, fd, c_out + (size_t)21 * HID,
                      h_out, c_out, h_bf, hs_bf, 5, 4, 1, 16);
    tail_bar(bar, 4);
    small_gemm_phase(hs_bf, h_bf + (size_t)5 * HID, Uib, Ufb, ioud, fd, 4, 16);
    tail_bar(bar, 5);
    combine_level_256(wx_iou, wx_f, ioud, fd, c_out + (size_t)5 * HID,
                      h_out, c_out, h_bf, hs_bf, 1, 1, 1, 16);
    tail_bar(bar, 6);
    small_gemm_phase(hs_bf, h_bf + (size_t)1 * HID, Uib, Ufb, ioud, fd, 1, 16);
    tail_bar(bar, 7);
    if (blockIdx.x == 0) {
        const int j = threadIdx.x * 2;
        #pragma unroll
        for (int c = 0; c < 2; ++c) {
            const int jj = j + c;
            float iv = wx_iou[jj]        + ioud[jj];
            float ov = wx_iou[512 + jj]  + ioud[512 + jj];
            float uv = wx_iou[1024 + jj] + ioud[1024 + jj];
            float wf = wx_f[jj];
            float fc = 0.f;
            #pragma unroll
            for (int q = 0; q < 4; ++q)
                fc += (wf + fd[(size_t)q * 512 + jj]) * c_out[(size_t)(q + 1) * 512 + jj];
            float ig = 1.f / (1.f + expf(-iv));
            float og = 1.f / (1.f + expf(-ov));
            float ug = tanhf(uv);
            float cv2 = ig * ug + fc;
            c_out[jj] = cv2;
            h_out[jj] = og * tanhf(cv2);
        }
    }
}

// ================= fallback-only kernels =================
__global__ void prep_kernel(const float* __restrict__ x,
                            const float* __restrict__ W_iou,
                            const float* __restrict__ W_f,
                            const float* __restrict__ U_iou,
                            const float* __restrict__ U_f,
                            float* __restrict__ h_leaf,
                            float* __restrict__ c_leaf,
                            unsigned short* __restrict__ dstb)
{
    prep_body(x, W_iou, W_f, U_iou, U_f, h_leaf, c_leaf, dstb);
}

__global__ __launch_bounds__(256) void gemm4_kernel(
    const unsigned short* __restrict__ hs_bf,
    const unsigned short* __restrict__ h5_bf,
    const unsigned short* __restrict__ Uib, const unsigned short* __restrict__ Ufb,
    float* __restrict__ ioud, float* __restrict__ fd)
{
    int b = blockIdx.x;
    if (b < 24) {
        gemm_tile_128(hs_bf, 256, Uib, nullptr, ioud, 1536, (b / 12) * 128, (b % 12) * 128);
    } else {
        int b2 = b - 24;
        gemm_tile_128(h5_bf, 1024, Ufb, nullptr, fd, 512, (b2 / 4) * 128, (b2 % 4) * 128);
    }
}

__global__ __launch_bounds__(256) void gemm_small_kernel(
    const unsigned short* __restrict__ hs_bf,
    const unsigned short* __restrict__ hch_bf,
    const unsigned short* __restrict__ Uib, const unsigned short* __restrict__ Ufb,
    float* __restrict__ ioud, float* __restrict__ fd, int nl)
{
    const int w = blockIdx.x * 4 + (threadIdx.x >> 6);
    const int mI = (nl + 15) >> 4;
    const int mF = (4 * nl + 15) >> 4;
    if (w < mI * 24) {
        direct_tile_16x64(hs_bf, nl, Uib, ioud, 1536, (w / 24) * 16, (w % 24) * 64);
    } else {
        int w2 = w - mI * 24;
        if (w2 < mF * 8)
            direct_tile_16x64(hch_bf, 4 * nl, Ufb, fd, 512, (w2 / 8) * 16, (w2 % 8) * 64);
    }
}

__global__ __launch_bounds__(128) void combine_root_kernel(
    const float* __restrict__ wx_iou, const float* __restrict__ wx_f,
    const float* __restrict__ ioud, const float* __restrict__ fd,
    const float* __restrict__ c_child,
    float* __restrict__ h_out, float* __restrict__ c_out)
{
    const int j4 = threadIdx.x << 2;
    #pragma unroll
    for (int c = 0; c < 4; ++c) {
        const int jj = j4 + c;
        float iv = wx_iou[jj]        + ioud[jj];
        float ov = wx_iou[512 + jj]  + ioud[512 + jj];
        float uv = wx_iou[1024 + jj] + ioud[1024 + jj];
        float wf = wx_f[jj];
        float fc = 0.f;
        #pragma unroll
        for (int q = 0; q < 4; ++q)
            fc += (wf + fd[(size_t)q * 512 + jj]) * c_child[(size_t)q * 512 + jj];
        float ig = 1.f / (1.f + expf(-iv));
        float og = 1.f / (1.f + expf(-ov));
        float ug = tanhf(uv);
        float cv2 = ig * ug + fc;
        c_out[jj] = cv2;
        h_out[jj] = og * tanhf(cv2);
    }
}

__global__ void zero_leaf_kernel(float* __restrict__ h_leaf, float* __restrict__ c_leaf)
{
    const size_t Z = (size_t)(N_NODES - N_INT) * HID / 4;
    const float4 zz = {0.f, 0.f, 0.f, 0.f};
    size_t i = (size_t)blockIdx.x * blockDim.x + threadIdx.x;
    const size_t stride = (size_t)gridDim.x * blockDim.x;
    for (; i < 2 * Z; i += stride) {
        if (i < Z) ((float4*)h_leaf)[i] = zz;
        else       ((float4*)c_leaf)[i - Z] = zz;
    }
}

extern "C" void kernel_launch(void* const* d_in, const int* in_sizes, int n_in,
                              void* d_out, int out_size, void* d_ws, size_t ws_size,
                              hipStream_t stream) {
    const float* x     = (const float*)d_in[0];
    // d_in[1] = children: deterministic (4n+1..4n+4), not needed
    const float* W_iou = (const float*)d_in[2];
    const float* b_iou = (const float*)d_in[3];
    const float* W_f   = (const float*)d_in[4];
    const float* b_f   = (const float*)d_in[5];
    const float* U_iou = (const float*)d_in[6];
    const float* U_f   = (const float*)d_in[7];

    float* h_out = (float*)d_out;                       // N_NODES x 512
    float* c_out = h_out + (size_t)N_NODES * HID;       // N_NODES x 512

    // ---- workspace layout (fp32 region, then contiguous bf16 cast region) ----
    float* ws     = (float*)d_ws;
    float* wx_iou = ws;                                  // 5461*1536 f32
    float* wx_f   = wx_iou + (size_t)N_INT * 1536;       // 1365*512  f32
    float* ioud   = wx_f   + (size_t)1365 * 512;         // 1024*1536 f32
    float* fd     = ioud   + (size_t)1024 * 1536;        // 4096*512  f32
    unsigned short* xb   = (unsigned short*)(fd + (size_t)4096 * 512);
    unsigned short* Wib  = xb  + (size_t)N_INT * 512;    // 1536*512 bf16
    unsigned short* Wfb  = Wib + (size_t)1536 * 512;     // 512*512
    unsigned short* Uib  = Wfb + (size_t)512 * 512;      // 1536*512
    unsigned short* Ufb  = Uib + (size_t)1536 * 512;     // 512*512
    unsigned short* h_bf = Ufb + (size_t)512 * 512;      // 5461*512
    unsigned short* hs_bf= h_bf + (size_t)N_INT * 512;   // 1024*512
    unsigned* bar = (unsigned*)(hs_bf + (size_t)1024 * 512);  // barrier lines (~8.6 KB)

    static int coopOK = -1;   // -1 unknown, 0 broken, 1 works

    // ---- dispatch 0: barrier counters (ws re-poisoned each iteration) ----
    bool barReady = false;
    if (coopOK != 0) {
        barReady = (hipMemsetAsync(bar, 0, 8704, stream) == hipSuccess);
        if (!barReady) { coopOK = 0; (void)hipGetLastError(); }
    }

    // ---- wide phases: dispatch boundaries (cheaper than 1024-block barriers) ----
    prep_cast_kernel<<<2048, 256, 0, stream>>>(x, W_iou, W_f, U_iou, U_f, xb);
    wgemm_kernel<<<560, 256, 0, stream>>>(xb, Wib, Wfb, b_iou, b_f, wx_iou, wx_f);
    combine_kernel_fb<<<1024, 256, 0, stream>>>(
        wx_iou, nullptr, nullptr, nullptr, nullptr,
        h_out, c_out, h_bf, hs_bf, 1365, 1024, 0);
    gemm5_kernel<<<224, 256, 0, stream>>>(hs_bf, h_bf + (size_t)1365 * HID, Uib, Ufb, ioud, fd);
    combine_kernel_fb<<<256, 256, 0, stream>>>(
        wx_iou, wx_f, ioud, fd, c_out + (size_t)1365 * HID,
        h_out, c_out, h_bf, hs_bf, 341, 256, 1);

    // ---- narrow phases: in-kernel barriers (cheap at <=64 arrivals) ----
    bool p56done = false, taildone = false;
    if (coopOK != 0 && barReady) {
        const unsigned short* h5_bf = h_bf + (size_t)341 * HID;
        void* a1[] = { (void*)&hs_bf, (void*)&h5_bf, (void*)&Uib, (void*)&Ufb,
                       (void*)&ioud, (void*)&fd, (void*)&wx_iou, (void*)&wx_f,
                       (void*)&c_out, (void*)&h_out, (void*)&h_bf, (void*)&bar };
        if (hipLaunchCooperativeKernel((const void*)p56_kernel,
                                       dim3(64), dim3(256), a1, 0, stream) == hipSuccess) {
            p56done = true;
            void* a2[] = { (void*)&hs_bf, (void*)&h_bf, (void*)&Uib, (void*)&Ufb,
                           (void*)&ioud, (void*)&fd, (void*)&wx_iou, (void*)&wx_f,
                           (void*)&h_out, (void*)&c_out, (void*)&bar };
            if (hipLaunchCooperativeKernel((const void*)tail_kernel,
                                           dim3(272), dim3(256), a2, 0, stream) == hipSuccess) {
                taildone = true;
                coopOK = 1;
            } else {
                coopOK = 0; (void)hipGetLastError();
            }
        } else {
            coopOK = 0; (void)hipGetLastError();
        }
    }

    if (!p56done) {
        gemm4_kernel<<<56, 256, 0, stream>>>(hs_bf, h_bf + (size_t)341 * HID, Uib, Ufb, ioud, fd);
        combine_kernel_fb<<<64, 256, 0, stream>>>(
            wx_iou, wx_f, ioud, fd, c_out + (size_t)341 * HID,
            h_out, c_out, h_bf, hs_bf, 85, 64, 1);
    }
    if (!taildone) {
        const int offs[9] = {0, 1, 5, 21, 85, 341, 1365, 5461, 21845};
        for (int l = 3; l >= 1; --l) {
            const int s  = offs[l];
            const int nl = offs[l + 1] - s;
            const int cb = offs[l + 1];
            const int mI = (nl + 15) >> 4;
            const int mF = (4 * nl + 15) >> 4;
            const int waves = mI * 24 + mF * 8;
            gemm_small_kernel<<<(waves + 3) / 4, 256, 0, stream>>>(
                hs_bf, h_bf + (size_t)cb * HID, Uib, Ufb, ioud, fd, nl);
            combine_kernel_fb<<<(nl + 3) / 4, 256, 0, stream>>>(
                wx_iou, wx_f, ioud, fd, c_out + (size_t)cb * HID,
                h_out, c_out, h_bf, hs_bf, s, nl >> 2, 1);
        }
        gemm_small_kernel<<<8, 256, 0, stream>>>(
            hs_bf, h_bf + (size_t)1 * HID, Uib, Ufb, ioud, fd, 1);
        combine_root_kernel<<<1, 128, 0, stream>>>(
            wx_iou, wx_f, ioud, fd, c_out + (size_t)1 * HID, h_out, c_out);
        zero_leaf_kernel<<<1024, 256, 0, stream>>>(
            h_out + (size_t)N_INT * HID, c_out + (size_t)N_INT * HID);
    }
}